// Round 3
// baseline (932.011 us; speedup 1.0000x reference)
//
#include <hip/hip_runtime.h>
#include <hip/hip_bf16.h>

#define B_  16
#define TQ_ 1024
#define TK_ 4096
#define D_  512

typedef unsigned short u16;
typedef __attribute__((ext_vector_type(8))) short short8;      // 8 bf16
typedef __attribute__((ext_vector_type(8))) _Float16 f16x8;    // 8 f16 (4 VGPRs)
typedef __attribute__((ext_vector_type(4))) float f32x4;

__device__ __forceinline__ u16 bf16_rne(float x) {
  unsigned u = __float_as_uint(x);
  u += 0x7FFFu + ((u >> 16) & 1u);
  return (u16)(u >> 16);
}
__device__ __forceinline__ float bf16_as_f32(u16 h) {
  return __uint_as_float(((unsigned)h) << 16);
}
__device__ __forceinline__ void split_bf16(float x, u16& h, u16& l) {
  u16 hh = bf16_rne(x);
  h = hh;
  l = bf16_rne(x - bf16_as_f32(hh));
}

// async global->LDS, 16B per lane; LDS dest must be wave-contiguous (base + lane*16)
__device__ __forceinline__ void glld16(const void* g, void* lds) {
  __builtin_amdgcn_global_load_lds(
      (const __attribute__((address_space(1))) unsigned int*)g,
      (__attribute__((address_space(3))) unsigned int*)lds, 16, 0, 0);
}

// 4-slot swizzle (64B rows, SBK=32): LDS slot (row,s) holds global segment
// s ^ (row&3) ^ ((row>>2)&3). Staging lane l fetches segment seg_src4(l);
// reads use slot qd ^ (ln&3) ^ (ln>>2). Conflict-free per 8-lane subgroup.
__device__ __forceinline__ int seg_src4(int l) {
  return (l & 3) ^ ((l >> 2) & 3) ^ ((l >> 4) & 3);
}

// ---------------------------------------------------------------------------
// enc [b][k][d] fp32 -> encT [b][d][k] f16  (+ optional encF16 [b][k][d] f16)
// ---------------------------------------------------------------------------
__global__ __launch_bounds__(256) void transpose_conv_kernel(
    const float* __restrict__ E, _Float16* __restrict__ ET,
    _Float16* __restrict__ EF)
{
  __shared__ float tile[64][65];
  const int b  = blockIdx.z;
  const int k0 = blockIdx.x * 64;
  const int d0 = blockIdx.y * 64;
  const float* Eb = E + (long long)b * TK_ * D_;
  _Float16* ETb = ET + (long long)b * D_ * TK_;

  const int t  = threadIdx.x;
  const int r  = t >> 2;          // 0..63
  const int c4 = (t & 3) * 16;    // 0,16,32,48

  __align__(16) _Float16 g[16];
  #pragma unroll
  for (int i = 0; i < 16; i += 4) {
    float4 v = *(const float4*)&Eb[(long long)(k0 + r) * D_ + d0 + c4 + i];
    tile[r][c4 + i + 0] = v.x;
    tile[r][c4 + i + 1] = v.y;
    tile[r][c4 + i + 2] = v.z;
    tile[r][c4 + i + 3] = v.w;
    g[i + 0] = (_Float16)v.x;
    g[i + 1] = (_Float16)v.y;
    g[i + 2] = (_Float16)v.z;
    g[i + 3] = (_Float16)v.w;
  }
  if (EF) {
    _Float16* EFb = EF + (long long)b * TK_ * D_;
    uint4* dstF = (uint4*)&EFb[(long long)(k0 + r) * D_ + d0 + c4];
    dstF[0] = ((const uint4*)g)[0];
    dstF[1] = ((const uint4*)g)[1];
  }
  __syncthreads();

  __align__(16) _Float16 h[16];
  #pragma unroll
  for (int i = 0; i < 16; ++i) h[i] = (_Float16)tile[c4 + i][r];
  uint4* dst = (uint4*)&ETb[(long long)(d0 + r) * TK_ + k0 + c4];
  dst[0] = ((const uint4*)h)[0];
  dst[1] = ((const uint4*)h)[1];
}

// ---------------------------------------------------------------------------
// dec2 = dec @ W^T  (split-bf16 triple), epilogue emits f16 hi/lo
// ---------------------------------------------------------------------------
#define DBM 128
#define DBN 128
#define DBK 32
#define DPAD 40

__global__ __launch_bounds__(256) void gemm_dec2_kernel(
    const float* __restrict__ A, const float* __restrict__ Bm,
    _Float16* __restrict__ Ch, _Float16* __restrict__ Cl)
{
  __shared__ u16 Ah[DBM * DPAD];
  __shared__ u16 Al[DBM * DPAD];
  __shared__ u16 Bh[DBN * DPAD];
  __shared__ u16 Bl[DBN * DPAD];

  const float* Ab = A  + (long long)(blockIdx.y * DBM) * D_;
  const float* Bb = Bm + (long long)(blockIdx.x * DBN) * D_;

  const int t    = threadIdx.x;
  const int r    = t >> 1;
  const int hf   = t & 1;
  const int lane = t & 63;
  const int wave = t >> 6;
  const int wr   = (wave >> 1) * 64;
  const int wc   = (wave & 1) * 64;
  const int ln   = lane & 15;
  const int qd   = lane >> 4;

  f32x4 acc[4][4];
  #pragma unroll
  for (int i = 0; i < 4; ++i)
    #pragma unroll
    for (int j = 0; j < 4; ++j) { f32x4 z = {0.f,0.f,0.f,0.f}; acc[i][j] = z; }

  const float* srcA = Ab + (long long)r * D_ + hf * 16;
  const float* srcB = Bb + (long long)r * D_ + hf * 16;
  u16* dAh = &Ah[r * DPAD + hf * 16];
  u16* dAl = &Al[r * DPAD + hf * 16];
  u16* dBh = &Bh[r * DPAD + hf * 16];
  u16* dBl = &Bl[r * DPAD + hf * 16];

  for (int k0 = 0; k0 < D_; k0 += DBK) {
    {
      __align__(16) u16 h[16], l[16];
      #pragma unroll
      for (int i = 0; i < 16; i += 4) {
        float4 v = *(const float4*)(srcA + k0 + i);
        split_bf16(v.x, h[i+0], l[i+0]);
        split_bf16(v.y, h[i+1], l[i+1]);
        split_bf16(v.z, h[i+2], l[i+2]);
        split_bf16(v.w, h[i+3], l[i+3]);
      }
      ((uint4*)dAh)[0] = ((const uint4*)h)[0];
      ((uint4*)dAh)[1] = ((const uint4*)h)[1];
      ((uint4*)dAl)[0] = ((const uint4*)l)[0];
      ((uint4*)dAl)[1] = ((const uint4*)l)[1];
      #pragma unroll
      for (int i = 0; i < 16; i += 4) {
        float4 v = *(const float4*)(srcB + k0 + i);
        split_bf16(v.x, h[i+0], l[i+0]);
        split_bf16(v.y, h[i+1], l[i+1]);
        split_bf16(v.z, h[i+2], l[i+2]);
        split_bf16(v.w, h[i+3], l[i+3]);
      }
      ((uint4*)dBh)[0] = ((const uint4*)h)[0];
      ((uint4*)dBh)[1] = ((const uint4*)h)[1];
      ((uint4*)dBl)[0] = ((const uint4*)l)[0];
      ((uint4*)dBl)[1] = ((const uint4*)l)[1];
    }
    __syncthreads();

    short8 fah[4], fal[4], fbh[4], fbl[4];
    #pragma unroll
    for (int i = 0; i < 4; ++i) {
      int ra = (wr + i * 16 + ln) * DPAD + qd * 8;
      int rb = (wc + i * 16 + ln) * DPAD + qd * 8;
      fah[i] = *(const short8*)&Ah[ra];
      fal[i] = *(const short8*)&Al[ra];
      fbh[i] = *(const short8*)&Bh[rb];
      fbl[i] = *(const short8*)&Bl[rb];
    }
    #pragma unroll
    for (int i = 0; i < 4; ++i)
      #pragma unroll
      for (int j = 0; j < 4; ++j) {
        acc[i][j] = __builtin_amdgcn_mfma_f32_16x16x32_bf16(fah[i], fbh[j], acc[i][j], 0, 0, 0);
        acc[i][j] = __builtin_amdgcn_mfma_f32_16x16x32_bf16(fah[i], fbl[j], acc[i][j], 0, 0, 0);
        acc[i][j] = __builtin_amdgcn_mfma_f32_16x16x32_bf16(fal[i], fbh[j], acc[i][j], 0, 0, 0);
      }
    __syncthreads();
  }

  const int m0 = blockIdx.y * DBM;
  const int n0 = blockIdx.x * DBN;
  #pragma unroll
  for (int i = 0; i < 4; ++i)
    #pragma unroll
    for (int j = 0; j < 4; ++j)
      #pragma unroll
      for (int rg = 0; rg < 4; ++rg) {
        int row = m0 + wr + i * 16 + qd * 4 + rg;
        int col = n0 + wc + j * 16 + ln;
        float x = acc[i][j][rg];
        _Float16 h = (_Float16)x;
        _Float16 l = (_Float16)(x - (float)h);
        long long idx = (long long)row * D_ + col;
        Ch[idx] = h;
        Cl[idx] = l;
      }
}

// ---------------------------------------------------------------------------
// Score GEMM: C[b][q][k] = sum_d dec2[b,q,d] * enc[b,k,d]
// 3-buffer pipeline, counted vmcnt (T4): loads stay in flight ~2 iters;
// raw s_barrier (no vmcnt drain), one barrier per k-iter. setprio on MFMA.
// ---------------------------------------------------------------------------
#define SBM 128
#define SBN 128
#define SBK 32
#define S_NT (D_ / SBK)   // 16

template<bool F16B>
__global__ __launch_bounds__(256) void gemm_score_kernel(
    const _Float16* __restrict__ A_h, const _Float16* __restrict__ A_l,
    const float* __restrict__ Bf, const _Float16* __restrict__ B16,
    float* __restrict__ C)
{
  __shared__ _Float16 sAh[3][SBM * SBK];   // 3 x 8 KB
  __shared__ _Float16 sAl[3][SBM * SBK];   // 3 x 8 KB
  __shared__ _Float16 sB [3][SBN * SBK];   // 3 x 8 KB

  const int bz = blockIdx.z;
  const int m0 = blockIdx.y * SBM;
  const int n0 = blockIdx.x * SBN;
  const _Float16* Ahb = A_h + (long long)bz * TQ_ * D_ + (long long)m0 * D_;
  const _Float16* Alb = A_l + (long long)bz * TQ_ * D_ + (long long)m0 * D_;

  const int t    = threadIdx.x;
  const int lane = t & 63;
  const int wave = t >> 6;
  const int wr   = (wave >> 1) * 64;
  const int wc   = (wave & 1) * 64;
  const int ln   = lane & 15;
  const int qd   = lane >> 4;
  const int sw   = qd ^ (ln & 3) ^ (ln >> 2);   // swizzled k-slot for reads

  f32x4 acc[4][4];
  #pragma unroll
  for (int i = 0; i < 4; ++i)
    #pragma unroll
    for (int j = 0; j < 4; ++j) { f32x4 z = {0.f,0.f,0.f,0.f}; acc[i][j] = z; }

  // glld mapping: wave handles chunks {2w,2w+1}; lane l -> row 16c+(l>>2),
  // global segment seg_src4(l), LDS linear dest = base + l*16.
  const int c0   = wave * 2;
  const int arow = c0 * 16 + (lane >> 2);
  const int ab   = seg_src4(lane) * 16;
  const char* gAh = (const char*)Ahb + (long long)arow * D_ * 2 + ab;
  const char* gAl = (const char*)Alb + (long long)arow * D_ * 2 + ab;
  const long long rstep = (long long)16 * D_ * 2;   // +16 rows
  const int dstoff = c0 * 1024 + lane * 16;

  const char* gB16 = nullptr;
  if constexpr (F16B) {
    const _Float16* Bb16 = B16 + (long long)bz * TK_ * D_ + (long long)n0 * D_;
    gB16 = (const char*)Bb16 + (long long)arow * D_ * 2 + ab;
  }

  // fallback B staging: thread t -> row t>>1, half t&1; swizzled store slots
  const float* Bb = Bf + (long long)bz * TK_ * D_ + (long long)n0 * D_;
  const int brow = t >> 1;
  const int bhf  = t & 1;
  const float* srcB = Bb + (long long)brow * D_ + bhf * 16;
  const int bh2 = (brow & 3) ^ ((brow >> 2) & 3);
  const int db0 = brow * SBK + ((2 * bhf    ) ^ bh2) * 8;
  const int db1 = brow * SBK + ((2 * bhf + 1) ^ bh2) * 8;

  // 6 glld per call (F16B): 4 A-plane + 2 B
  auto stage = [&](int buf, int k0) {
    const long long ko = (long long)k0 * 2;
    char* dAh = (char*)sAh[buf] + dstoff;
    char* dAl = (char*)sAl[buf] + dstoff;
    glld16(gAh + ko, dAh);
    glld16(gAh + ko + rstep, dAh + 1024);
    glld16(gAl + ko, dAl);
    glld16(gAl + ko + rstep, dAl + 1024);
    if constexpr (F16B) {
      char* dBv = (char*)sB[buf] + dstoff;
      glld16(gB16 + ko, dBv);
      glld16(gB16 + ko + rstep, dBv + 1024);
    } else {
      __align__(16) _Float16 hb[16];
      #pragma unroll
      for (int i = 0; i < 16; i += 4) {
        float4 v = *(const float4*)(srcB + k0 + i);
        hb[i+0] = (_Float16)v.x;
        hb[i+1] = (_Float16)v.y;
        hb[i+2] = (_Float16)v.z;
        hb[i+3] = (_Float16)v.w;
      }
      *(uint4*)&sB[buf][db0] = ((const uint4*)hb)[0];
      *(uint4*)&sB[buf][db1] = ((const uint4*)hb)[1];
    }
  };

  stage(0, 0);
  stage(1, SBK);
  if constexpr (F16B) {
    asm volatile("s_waitcnt vmcnt(6)" ::: "memory");     // tile0's 6 done
  } else {
    asm volatile("s_waitcnt vmcnt(0) lgkmcnt(0)" ::: "memory");
  }
  __builtin_amdgcn_s_barrier();
  __builtin_amdgcn_sched_barrier(0);

  #pragma unroll
  for (int tt = 0; tt < S_NT; ++tt) {
    const int cur = tt % 3;
    const int nxt = (tt + 2) % 3;
    // stage tile tt+2 into the buffer of tile tt-1 (reads drained at the
    // last barrier; glld cannot hoist across the mem-clobber asm there)
    if (tt + 2 < S_NT) stage(nxt, (tt + 2) * SBK);

    const _Float16* bAh = sAh[cur];
    const _Float16* bAl = sAl[cur];
    const _Float16* bBv = sB[cur];
    f16x8 fah[4], fal[4], fb[4];
    #pragma unroll
    for (int i = 0; i < 4; ++i) {
      const int ra = (wr + i * 16 + ln) * SBK + sw * 8;
      const int rb = (wc + i * 16 + ln) * SBK + sw * 8;
      fah[i] = *(const f16x8*)&bAh[ra];
      fal[i] = *(const f16x8*)&bAl[ra];
      fb[i]  = *(const f16x8*)&bBv[rb];
    }
    __builtin_amdgcn_s_setprio(1);
    #pragma unroll
    for (int i = 0; i < 4; ++i)
      #pragma unroll
      for (int j = 0; j < 4; ++j) {
        acc[i][j] = __builtin_amdgcn_mfma_f32_16x16x32_f16(fah[i], fb[j], acc[i][j], 0, 0, 0);
        acc[i][j] = __builtin_amdgcn_mfma_f32_16x16x32_f16(fal[i], fb[j], acc[i][j], 0, 0, 0);
      }
    __builtin_amdgcn_s_setprio(0);
    if (tt + 1 < S_NT) {
      if constexpr (F16B) {
        if (tt + 2 < S_NT) {
          asm volatile("s_waitcnt vmcnt(6)" ::: "memory");  // tile tt+1 landed
        } else {
          asm volatile("s_waitcnt vmcnt(0)" ::: "memory");
        }
      } else {
        asm volatile("s_waitcnt vmcnt(0) lgkmcnt(0)" ::: "memory");
      }
      __builtin_amdgcn_s_barrier();
      __builtin_amdgcn_sched_barrier(0);
    }
  }

  float* Cb = C + (long long)bz * TQ_ * TK_;
  #pragma unroll
  for (int i = 0; i < 4; ++i)
    #pragma unroll
    for (int j = 0; j < 4; ++j)
      #pragma unroll
      for (int rg = 0; rg < 4; ++rg) {
        int row = m0 + wr + i * 16 + qd * 4 + rg;
        int col = n0 + wc + j * 16 + ln;
        Cb[(long long)row * TK_ + col] = acc[i][j][rg];
      }
}

// ---------------------------------------------------------------------------
// Row softmax in place (+ optional f16 copy for ctx GEMM)
// ---------------------------------------------------------------------------
template<bool WP16>
__global__ __launch_bounds__(256) void softmax_kernel(
    float* __restrict__ P, _Float16* __restrict__ P16)
{
  __shared__ float red[8];
  float* p = P + (long long)blockIdx.x * TK_;
  const int t    = threadIdx.x;
  const int lane = t & 63;
  const int wave = t >> 6;

  float4 v[4];
  float mx = -3.0e38f;
  #pragma unroll
  for (int i = 0; i < 4; ++i) {
    v[i] = *(const float4*)&p[i * 1024 + t * 4];
    mx = fmaxf(mx, fmaxf(fmaxf(v[i].x, v[i].y), fmaxf(v[i].z, v[i].w)));
  }
  #pragma unroll
  for (int o = 32; o > 0; o >>= 1) mx = fmaxf(mx, __shfl_xor(mx, o, 64));
  if (lane == 0) red[wave] = mx;
  __syncthreads();
  mx = fmaxf(fmaxf(red[0], red[1]), fmaxf(red[2], red[3]));

  float s = 0.f;
  #pragma unroll
  for (int i = 0; i < 4; ++i) {
    v[i].x = __expf(v[i].x - mx);
    v[i].y = __expf(v[i].y - mx);
    v[i].z = __expf(v[i].z - mx);
    v[i].w = __expf(v[i].w - mx);
    s += (v[i].x + v[i].y) + (v[i].z + v[i].w);
  }
  #pragma unroll
  for (int o = 32; o > 0; o >>= 1) s += __shfl_xor(s, o, 64);
  if (lane == 0) red[4 + wave] = s;
  __syncthreads();
  s = (red[4] + red[5]) + (red[6] + red[7]);
  const float inv = 1.0f / s;

  _Float16* p16 = WP16 ? (P16 + (long long)blockIdx.x * TK_) : nullptr;
  #pragma unroll
  for (int i = 0; i < 4; ++i) {
    v[i].x *= inv; v[i].y *= inv; v[i].z *= inv; v[i].w *= inv;
    *(float4*)&p[i * 1024 + t * 4] = v[i];
    if constexpr (WP16) {
      union { _Float16 h[4]; uint2 u; } pk;
      pk.h[0] = (_Float16)v[i].x;
      pk.h[1] = (_Float16)v[i].y;
      pk.h[2] = (_Float16)v[i].z;
      pk.h[3] = (_Float16)v[i].w;
      *(uint2*)&p16[i * 1024 + t * 4] = pk.u;
    }
  }
}

// ---------------------------------------------------------------------------
// Context GEMM: C[b][q][d] = sum_k P[b,q,k] * encT[b,d,k]
// Tile 64x256, CBK=64, 512 thr (8 waves 2x4). 3-buffer counted-vmcnt
// pipeline (5 glld/tile), raw barriers, 8-slot XOR swizzle (128B rows).
// XCD-chunked 1-D grid, m-fastest decode.
// ---------------------------------------------------------------------------
#define CBM 64
#define CBN 256
#define CBK 64
#define C_NT (TK_ / CBK)   // 64

template<bool F16A>
__global__ __launch_bounds__(512) void gemm_ctx_kernel(
    const float* __restrict__ P, const _Float16* __restrict__ P16,
    const _Float16* __restrict__ ET, float* __restrict__ C)
{
  __shared__ _Float16 sA[3][CBM * CBK];   // 3 x 8 KB
  __shared__ _Float16 sB[3][CBN * CBK];   // 3 x 32 KB

  const int bid = blockIdx.x;
  const int s   = (bid & 7) * 64 + (bid >> 3);
  const int m0  = (s & 15) * CBM;
  const int n0  = ((s >> 4) & 1) * CBN;
  const int bz  = s >> 5;

  const float*    Pb = P  + (long long)bz * TQ_ * TK_ + (long long)m0 * TK_;
  const _Float16* Eb = ET + (long long)bz * D_ * TK_  + (long long)n0 * TK_;

  const int t    = threadIdx.x;
  const int lane = t & 63;
  const int wave = t >> 6;
  const int wr   = (wave >> 2) * 32;   // 0,32
  const int wc   = (wave & 3) * 64;    // 0,64,128,192
  const int ln   = lane & 15;
  const int qd   = lane >> 4;
  const int l7   = ln & 7;

  f32x4 acc[2][4];
  #pragma unroll
  for (int i = 0; i < 2; ++i)
    #pragma unroll
    for (int j = 0; j < 4; ++j) { f32x4 z = {0.f,0.f,0.f,0.f}; acc[i][j] = z; }

  // staging geometry: 1 KB chunk = 8 rows x 128 B; lane l -> row 8c+(l>>3),
  // stored slot l&7, fetched global segment (l&7)^((l>>3)&7).
  const int l8   = lane >> 3;          // 0..7
  const int sseg = (lane & 7) ^ l8;    // inverse-swizzled global segment
  const char* gB = (const char*)Eb + ((long long)(wave * 32 + l8) * TK_) * 2 + sseg * 16;
  const long long bstep = (long long)8 * TK_ * 2;
  const int bdst = wave * 4096 + lane * 16;
  const char* gA16 = nullptr;
  if constexpr (F16A) {
    const _Float16* Pb16 = P16 + (long long)bz * TQ_ * TK_ + (long long)m0 * TK_;
    gA16 = (const char*)Pb16 + ((long long)(wave * 8 + l8) * TK_) * 2 + sseg * 16;
  }
  const int adst = wave * 1024 + lane * 16;

  // A fallback: thread t -> row t>>3 (0..63), logical slot t&7 (8 floats)
  const int arowf = t >> 3;
  const int asegf = t & 7;
  const float* gAf = Pb + (long long)arowf * TK_ + asegf * 8;
  const int afoff = arowf * CBK + ((asegf ^ (arowf & 7)) * 8);

  // 5 glld per call (F16A): 4 B + 1 A
  auto stage = [&](int buf, int k0) {
    const long long ko = (long long)k0 * 2;
    char* dB = (char*)sB[buf] + bdst;
    #pragma unroll
    for (int j = 0; j < 4; ++j)
      glld16(gB + ko + j * bstep, dB + j * 1024);
    if constexpr (F16A) {
      glld16(gA16 + ko, (char*)sA[buf] + adst);
    } else {
      float4 v0 = *(const float4*)(gAf + k0);
      float4 v1 = *(const float4*)(gAf + k0 + 4);
      __align__(16) _Float16 hb[8];
      hb[0] = (_Float16)v0.x; hb[1] = (_Float16)v0.y;
      hb[2] = (_Float16)v0.z; hb[3] = (_Float16)v0.w;
      hb[4] = (_Float16)v1.x; hb[5] = (_Float16)v1.y;
      hb[6] = (_Float16)v1.z; hb[7] = (_Float16)v1.w;
      *(uint4*)&sA[buf][afoff] = *(const uint4*)hb;
    }
  };

  stage(0, 0);
  stage(1, CBK);
  if constexpr (F16A) {
    asm volatile("s_waitcnt vmcnt(5)" ::: "memory");     // tile0's 5 done
  } else {
    asm volatile("s_waitcnt vmcnt(0) lgkmcnt(0)" ::: "memory");
  }
  __builtin_amdgcn_s_barrier();
  __builtin_amdgcn_sched_barrier(0);

  int cur = 0, nxt = 2;
  #pragma unroll 1
  for (int tt = 0; tt < C_NT; ++tt) {
    if (tt + 2 < C_NT) stage(nxt, (tt + 2) * CBK);

    const _Float16* bA  = sA[cur];
    const _Float16* bBv = sB[cur];
    f16x8 fa[2][2], fb[4][2];
    #pragma unroll
    for (int i = 0; i < 2; ++i)
      #pragma unroll
      for (int kk = 0; kk < 2; ++kk)
        fa[i][kk] = *(const f16x8*)&bA[(wr + i * 16 + ln) * CBK + (((kk * 4 + qd) ^ l7) * 8)];
    #pragma unroll
    for (int j = 0; j < 4; ++j)
      #pragma unroll
      for (int kk = 0; kk < 2; ++kk)
        fb[j][kk] = *(const f16x8*)&bBv[(wc + j * 16 + ln) * CBK + (((kk * 4 + qd) ^ l7) * 8)];
    __builtin_amdgcn_s_setprio(1);
    #pragma unroll
    for (int i = 0; i < 2; ++i)
      #pragma unroll
      for (int j = 0; j < 4; ++j)
        #pragma unroll
        for (int kk = 0; kk < 2; ++kk)
          acc[i][j] = __builtin_amdgcn_mfma_f32_16x16x32_f16(fa[i][kk], fb[j][kk], acc[i][j], 0, 0, 0);
    __builtin_amdgcn_s_setprio(0);
    if (tt + 1 < C_NT) {
      if constexpr (F16A) {
        if (tt + 2 < C_NT) {
          asm volatile("s_waitcnt vmcnt(5)" ::: "memory");  // tile tt+1 landed
        } else {
          asm volatile("s_waitcnt vmcnt(0)" ::: "memory");
        }
      } else {
        asm volatile("s_waitcnt vmcnt(0) lgkmcnt(0)" ::: "memory");
      }
      __builtin_amdgcn_s_barrier();
      __builtin_amdgcn_sched_barrier(0);
    }
    cur = (cur == 2) ? 0 : cur + 1;
    nxt = (nxt == 2) ? 0 : nxt + 1;
  }

  float* Cb = C + (long long)bz * TQ_ * D_;
  #pragma unroll
  for (int i = 0; i < 2; ++i)
    #pragma unroll
    for (int j = 0; j < 4; ++j)
      #pragma unroll
      for (int rg = 0; rg < 4; ++rg) {
        int row = m0 + wr + i * 16 + qd * 4 + rg;
        int col = n0 + wc + j * 16 + ln;
        Cb[(long long)row * D_ + col] = acc[i][j][rg];
      }
}

// ---------------------------------------------------------------------------
extern "C" void kernel_launch(void* const* d_in, const int* in_sizes, int n_in,
                              void* d_out, int out_size, void* d_ws, size_t ws_size,
                              hipStream_t stream) {
  (void)in_sizes; (void)n_in; (void)out_size;
  const float* dec = (const float*)d_in[0];   // [16,1024,512]
  const float* enc = (const float*)d_in[1];   // [16,4096,512]
  const float* Wa  = (const float*)d_in[2];   // [512,512]
  // b_a constant along softmax axis -> cancels exactly; unused.

  float* ctx   = (float*)d_out;                                   // [16,1024,512]
  float* align = ctx + (long long)B_ * TQ_ * D_;                  // [16,1024,4096]

  char* ws = (char*)d_ws;
  const size_t SZ_ENCT = (size_t)B_ * D_ * TK_ * 2;   // 67,108,864
  const size_t SZ_DEC2 = (size_t)B_ * TQ_ * D_ * 2;   // 16,777,216
  const size_t SZ_ENCF = (size_t)B_ * TK_ * D_ * 2;   // 67,108,864
  const size_t SZ_P16  = (size_t)B_ * TQ_ * TK_ * 2;  // 134,217,728

  _Float16* encT  = (_Float16*)(ws);
  _Float16* dec2h = (_Float16*)(ws + SZ_ENCT);
  _Float16* dec2l = (_Float16*)(ws + SZ_ENCT + SZ_DEC2);
  _Float16* encF  = (_Float16*)(ws + SZ_ENCT + 2 * SZ_DEC2);
  // P16 overlays dec2h/dec2l/encF -- all dead once score finishes (stream order)
  _Float16* p16   = (_Float16*)(ws + SZ_ENCT);

  const bool mid  = ws_size >= SZ_ENCT + 2 * SZ_DEC2 + SZ_ENCF;  // 167.8 MB
  const bool full = ws_size >= SZ_ENCT + SZ_P16;                  // 201.3 MB

  // 1) encT[b][d][k] = f16(enc[b][k][d]); also encF16[b][k][d] if room
  transpose_conv_kernel<<<dim3(TK_ / 64, D_ / 64, B_), 256, 0, stream>>>(
      enc, encT, mid ? encF : nullptr);

  // 2) dec2 = dec @ W^T (split-bf16 triple), epilogue -> f16 hi/lo planes
  gemm_dec2_kernel<<<dim3(D_ / DBN, (B_ * TQ_) / DBM, 1), 256, 0, stream>>>(
      dec, Wa, dec2h, dec2l);

  // 3) score = dec2 @ enc^T (f16: Ah*B + Al*B)
  if (mid)
    gemm_score_kernel<true><<<dim3(TK_ / SBN, TQ_ / SBM, B_), 256, 0, stream>>>(
        dec2h, dec2l, enc, encF, align);
  else
    gemm_score_kernel<false><<<dim3(TK_ / SBN, TQ_ / SBM, B_), 256, 0, stream>>>(
        dec2h, dec2l, enc, nullptr, align);

  // 4) softmax rows in place (+ f16 copy if room)
  if (full)
    softmax_kernel<true><<<B_ * TQ_, 256, 0, stream>>>(align, p16);
  else
    softmax_kernel<false><<<B_ * TQ_, 256, 0, stream>>>(align, nullptr);

  // 5) ctx = P @ encT^T (f16), 1-D grid with XCD chunk swizzle
  if (full)
    gemm_ctx_kernel<true><<<dim3((TQ_ / CBM) * (D_ / CBN) * B_), 512, 0, stream>>>(
        align, p16, encT, ctx);
  else
    gemm_ctx_kernel<false><<<dim3((TQ_ / CBM) * (D_ / CBN) * B_), 512, 0, stream>>>(
        align, nullptr, encT, ctx);
}

// Round 4
// 868.782 us; speedup vs baseline: 1.0728x; 1.0728x over previous
//
#include <hip/hip_runtime.h>
#include <hip/hip_bf16.h>

#define B_  16
#define TQ_ 1024
#define TK_ 4096
#define D_  512

typedef unsigned short u16;
typedef __attribute__((ext_vector_type(8))) short short8;      // 8 bf16
typedef __attribute__((ext_vector_type(8))) _Float16 f16x8;    // 8 f16 (4 VGPRs)
typedef __attribute__((ext_vector_type(4))) float f32x4;

__device__ __forceinline__ u16 bf16_rne(float x) {
  unsigned u = __float_as_uint(x);
  u += 0x7FFFu + ((u >> 16) & 1u);
  return (u16)(u >> 16);
}
__device__ __forceinline__ float bf16_as_f32(u16 h) {
  return __uint_as_float(((unsigned)h) << 16);
}
__device__ __forceinline__ void split_bf16(float x, u16& h, u16& l) {
  u16 hh = bf16_rne(x);
  h = hh;
  l = bf16_rne(x - bf16_as_f32(hh));
}

// async global->LDS, 16B per lane; LDS dest must be wave-contiguous (base + lane*16)
__device__ __forceinline__ void glld16(const void* g, void* lds) {
  __builtin_amdgcn_global_load_lds(
      (const __attribute__((address_space(1))) unsigned int*)g,
      (__attribute__((address_space(3))) unsigned int*)lds, 16, 0, 0);
}

// 4-slot swizzle (64B rows, BK=32): LDS slot (row,s) holds global segment
// s ^ (row&3) ^ ((row>>2)&3). Staging lane l fetches segment seg_src4(l);
// reads use slot qd ^ (ln&3) ^ (ln>>2). Conflict-free per 8-lane subgroup.
__device__ __forceinline__ int seg_src4(int l) {
  return (l & 3) ^ ((l >> 2) & 3) ^ ((l >> 4) & 3);
}

// ---------------------------------------------------------------------------
// enc [b][k][d] fp32 -> encT [b][d][k] f16  (+ optional encF16 [b][k][d] f16)
// ---------------------------------------------------------------------------
__global__ __launch_bounds__(256) void transpose_conv_kernel(
    const float* __restrict__ E, _Float16* __restrict__ ET,
    _Float16* __restrict__ EF)
{
  __shared__ float tile[64][65];
  const int b  = blockIdx.z;
  const int k0 = blockIdx.x * 64;
  const int d0 = blockIdx.y * 64;
  const float* Eb = E + (long long)b * TK_ * D_;
  _Float16* ETb = ET + (long long)b * D_ * TK_;

  const int t  = threadIdx.x;
  const int r  = t >> 2;          // 0..63
  const int c4 = (t & 3) * 16;    // 0,16,32,48

  __align__(16) _Float16 g[16];
  #pragma unroll
  for (int i = 0; i < 16; i += 4) {
    float4 v = *(const float4*)&Eb[(long long)(k0 + r) * D_ + d0 + c4 + i];
    tile[r][c4 + i + 0] = v.x;
    tile[r][c4 + i + 1] = v.y;
    tile[r][c4 + i + 2] = v.z;
    tile[r][c4 + i + 3] = v.w;
    g[i + 0] = (_Float16)v.x;
    g[i + 1] = (_Float16)v.y;
    g[i + 2] = (_Float16)v.z;
    g[i + 3] = (_Float16)v.w;
  }
  if (EF) {
    _Float16* EFb = EF + (long long)b * TK_ * D_;
    uint4* dstF = (uint4*)&EFb[(long long)(k0 + r) * D_ + d0 + c4];
    dstF[0] = ((const uint4*)g)[0];
    dstF[1] = ((const uint4*)g)[1];
  }
  __syncthreads();

  __align__(16) _Float16 h[16];
  #pragma unroll
  for (int i = 0; i < 16; ++i) h[i] = (_Float16)tile[c4 + i][r];
  uint4* dst = (uint4*)&ETb[(long long)(d0 + r) * TK_ + k0 + c4];
  dst[0] = ((const uint4*)h)[0];
  dst[1] = ((const uint4*)h)[1];
}

// ---------------------------------------------------------------------------
// dec2 = dec @ W^T  (split-bf16 triple), epilogue emits f16 hi/lo
// ---------------------------------------------------------------------------
#define DBM 128
#define DBN 128
#define DBK 32
#define DPAD 40

__global__ __launch_bounds__(256) void gemm_dec2_kernel(
    const float* __restrict__ A, const float* __restrict__ Bm,
    _Float16* __restrict__ Ch, _Float16* __restrict__ Cl)
{
  __shared__ u16 Ah[DBM * DPAD];
  __shared__ u16 Al[DBM * DPAD];
  __shared__ u16 Bh[DBN * DPAD];
  __shared__ u16 Bl[DBN * DPAD];

  const float* Ab = A  + (long long)(blockIdx.y * DBM) * D_;
  const float* Bb = Bm + (long long)(blockIdx.x * DBN) * D_;

  const int t    = threadIdx.x;
  const int r    = t >> 1;
  const int hf   = t & 1;
  const int lane = t & 63;
  const int wave = t >> 6;
  const int wr   = (wave >> 1) * 64;
  const int wc   = (wave & 1) * 64;
  const int ln   = lane & 15;
  const int qd   = lane >> 4;

  f32x4 acc[4][4];
  #pragma unroll
  for (int i = 0; i < 4; ++i)
    #pragma unroll
    for (int j = 0; j < 4; ++j) { f32x4 z = {0.f,0.f,0.f,0.f}; acc[i][j] = z; }

  const float* srcA = Ab + (long long)r * D_ + hf * 16;
  const float* srcB = Bb + (long long)r * D_ + hf * 16;
  u16* dAh = &Ah[r * DPAD + hf * 16];
  u16* dAl = &Al[r * DPAD + hf * 16];
  u16* dBh = &Bh[r * DPAD + hf * 16];
  u16* dBl = &Bl[r * DPAD + hf * 16];

  for (int k0 = 0; k0 < D_; k0 += DBK) {
    {
      __align__(16) u16 h[16], l[16];
      #pragma unroll
      for (int i = 0; i < 16; i += 4) {
        float4 v = *(const float4*)(srcA + k0 + i);
        split_bf16(v.x, h[i+0], l[i+0]);
        split_bf16(v.y, h[i+1], l[i+1]);
        split_bf16(v.z, h[i+2], l[i+2]);
        split_bf16(v.w, h[i+3], l[i+3]);
      }
      ((uint4*)dAh)[0] = ((const uint4*)h)[0];
      ((uint4*)dAh)[1] = ((const uint4*)h)[1];
      ((uint4*)dAl)[0] = ((const uint4*)l)[0];
      ((uint4*)dAl)[1] = ((const uint4*)l)[1];
      #pragma unroll
      for (int i = 0; i < 16; i += 4) {
        float4 v = *(const float4*)(srcB + k0 + i);
        split_bf16(v.x, h[i+0], l[i+0]);
        split_bf16(v.y, h[i+1], l[i+1]);
        split_bf16(v.z, h[i+2], l[i+2]);
        split_bf16(v.w, h[i+3], l[i+3]);
      }
      ((uint4*)dBh)[0] = ((const uint4*)h)[0];
      ((uint4*)dBh)[1] = ((const uint4*)h)[1];
      ((uint4*)dBl)[0] = ((const uint4*)l)[0];
      ((uint4*)dBl)[1] = ((const uint4*)l)[1];
    }
    __syncthreads();

    short8 fah[4], fal[4], fbh[4], fbl[4];
    #pragma unroll
    for (int i = 0; i < 4; ++i) {
      int ra = (wr + i * 16 + ln) * DPAD + qd * 8;
      int rb = (wc + i * 16 + ln) * DPAD + qd * 8;
      fah[i] = *(const short8*)&Ah[ra];
      fal[i] = *(const short8*)&Al[ra];
      fbh[i] = *(const short8*)&Bh[rb];
      fbl[i] = *(const short8*)&Bl[rb];
    }
    #pragma unroll
    for (int i = 0; i < 4; ++i)
      #pragma unroll
      for (int j = 0; j < 4; ++j) {
        acc[i][j] = __builtin_amdgcn_mfma_f32_16x16x32_bf16(fah[i], fbh[j], acc[i][j], 0, 0, 0);
        acc[i][j] = __builtin_amdgcn_mfma_f32_16x16x32_bf16(fah[i], fbl[j], acc[i][j], 0, 0, 0);
        acc[i][j] = __builtin_amdgcn_mfma_f32_16x16x32_bf16(fal[i], fbh[j], acc[i][j], 0, 0, 0);
      }
    __syncthreads();
  }

  const int m0 = blockIdx.y * DBM;
  const int n0 = blockIdx.x * DBN;
  #pragma unroll
  for (int i = 0; i < 4; ++i)
    #pragma unroll
    for (int j = 0; j < 4; ++j)
      #pragma unroll
      for (int rg = 0; rg < 4; ++rg) {
        int row = m0 + wr + i * 16 + qd * 4 + rg;
        int col = n0 + wc + j * 16 + ln;
        float x = acc[i][j][rg];
        _Float16 h = (_Float16)x;
        _Float16 l = (_Float16)(x - (float)h);
        long long idx = (long long)row * D_ + col;
        Ch[idx] = h;
        Cl[idx] = l;
      }
}

// ---------------------------------------------------------------------------
// Score GEMM: C[b][q][k] = sum_d dec2[b,q,d] * enc[b,k,d]
// 3-buffer pipeline, counted vmcnt (T4): loads stay in flight ~2 iters;
// raw s_barrier (no vmcnt drain), one barrier per k-iter. setprio on MFMA.
// ---------------------------------------------------------------------------
#define SBM 128
#define SBN 128
#define SBK 32
#define S_NT (D_ / SBK)   // 16

template<bool F16B>
__global__ __launch_bounds__(256) void gemm_score_kernel(
    const _Float16* __restrict__ A_h, const _Float16* __restrict__ A_l,
    const float* __restrict__ Bf, const _Float16* __restrict__ B16,
    float* __restrict__ C)
{
  __shared__ _Float16 sAh[3][SBM * SBK];   // 3 x 8 KB
  __shared__ _Float16 sAl[3][SBM * SBK];   // 3 x 8 KB
  __shared__ _Float16 sB [3][SBN * SBK];   // 3 x 8 KB

  const int bz = blockIdx.z;
  const int m0 = blockIdx.y * SBM;
  const int n0 = blockIdx.x * SBN;
  const _Float16* Ahb = A_h + (long long)bz * TQ_ * D_ + (long long)m0 * D_;
  const _Float16* Alb = A_l + (long long)bz * TQ_ * D_ + (long long)m0 * D_;

  const int t    = threadIdx.x;
  const int lane = t & 63;
  const int wave = t >> 6;
  const int wr   = (wave >> 1) * 64;
  const int wc   = (wave & 1) * 64;
  const int ln   = lane & 15;
  const int qd   = lane >> 4;
  const int sw   = qd ^ (ln & 3) ^ (ln >> 2);   // swizzled k-slot for reads

  f32x4 acc[4][4];
  #pragma unroll
  for (int i = 0; i < 4; ++i)
    #pragma unroll
    for (int j = 0; j < 4; ++j) { f32x4 z = {0.f,0.f,0.f,0.f}; acc[i][j] = z; }

  // glld mapping: wave handles chunks {2w,2w+1}; lane l -> row 16c+(l>>2),
  // global segment seg_src4(l), LDS linear dest = base + l*16.
  const int c0   = wave * 2;
  const int arow = c0 * 16 + (lane >> 2);
  const int ab   = seg_src4(lane) * 16;
  const char* gAh = (const char*)Ahb + (long long)arow * D_ * 2 + ab;
  const char* gAl = (const char*)Alb + (long long)arow * D_ * 2 + ab;
  const long long rstep = (long long)16 * D_ * 2;   // +16 rows
  const int dstoff = c0 * 1024 + lane * 16;

  const char* gB16 = nullptr;
  if constexpr (F16B) {
    const _Float16* Bb16 = B16 + (long long)bz * TK_ * D_ + (long long)n0 * D_;
    gB16 = (const char*)Bb16 + (long long)arow * D_ * 2 + ab;
  }

  // fallback B staging: thread t -> row t>>1, half t&1; swizzled store slots
  const float* Bb = Bf + (long long)bz * TK_ * D_ + (long long)n0 * D_;
  const int brow = t >> 1;
  const int bhf  = t & 1;
  const float* srcB = Bb + (long long)brow * D_ + bhf * 16;
  const int bh2 = (brow & 3) ^ ((brow >> 2) & 3);
  const int db0 = brow * SBK + ((2 * bhf    ) ^ bh2) * 8;
  const int db1 = brow * SBK + ((2 * bhf + 1) ^ bh2) * 8;

  // 6 glld per call (F16B): 4 A-plane + 2 B
  auto stage = [&](int buf, int k0) {
    const long long ko = (long long)k0 * 2;
    char* dAh = (char*)sAh[buf] + dstoff;
    char* dAl = (char*)sAl[buf] + dstoff;
    glld16(gAh + ko, dAh);
    glld16(gAh + ko + rstep, dAh + 1024);
    glld16(gAl + ko, dAl);
    glld16(gAl + ko + rstep, dAl + 1024);
    if constexpr (F16B) {
      char* dBv = (char*)sB[buf] + dstoff;
      glld16(gB16 + ko, dBv);
      glld16(gB16 + ko + rstep, dBv + 1024);
    } else {
      __align__(16) _Float16 hb[16];
      #pragma unroll
      for (int i = 0; i < 16; i += 4) {
        float4 v = *(const float4*)(srcB + k0 + i);
        hb[i+0] = (_Float16)v.x;
        hb[i+1] = (_Float16)v.y;
        hb[i+2] = (_Float16)v.z;
        hb[i+3] = (_Float16)v.w;
      }
      *(uint4*)&sB[buf][db0] = ((const uint4*)hb)[0];
      *(uint4*)&sB[buf][db1] = ((const uint4*)hb)[1];
    }
  };

  stage(0, 0);
  stage(1, SBK);
  if constexpr (F16B) {
    asm volatile("s_waitcnt vmcnt(6)" ::: "memory");     // tile0's 6 done
  } else {
    asm volatile("s_waitcnt vmcnt(0) lgkmcnt(0)" ::: "memory");
  }
  __builtin_amdgcn_s_barrier();
  __builtin_amdgcn_sched_barrier(0);

  #pragma unroll
  for (int tt = 0; tt < S_NT; ++tt) {
    const int cur = tt % 3;
    const int nxt = (tt + 2) % 3;
    // stage tile tt+2 into the buffer of tile tt-1 (reads drained at the
    // last barrier; glld cannot hoist across the mem-clobber asm there)
    if (tt + 2 < S_NT) stage(nxt, (tt + 2) * SBK);

    const _Float16* bAh = sAh[cur];
    const _Float16* bAl = sAl[cur];
    const _Float16* bBv = sB[cur];
    f16x8 fah[4], fal[4], fb[4];
    #pragma unroll
    for (int i = 0; i < 4; ++i) {
      const int ra = (wr + i * 16 + ln) * SBK + sw * 8;
      const int rb = (wc + i * 16 + ln) * SBK + sw * 8;
      fah[i] = *(const f16x8*)&bAh[ra];
      fal[i] = *(const f16x8*)&bAl[ra];
      fb[i]  = *(const f16x8*)&bBv[rb];
    }
    __builtin_amdgcn_s_setprio(1);
    #pragma unroll
    for (int i = 0; i < 4; ++i)
      #pragma unroll
      for (int j = 0; j < 4; ++j) {
        acc[i][j] = __builtin_amdgcn_mfma_f32_16x16x32_f16(fah[i], fb[j], acc[i][j], 0, 0, 0);
        acc[i][j] = __builtin_amdgcn_mfma_f32_16x16x32_f16(fal[i], fb[j], acc[i][j], 0, 0, 0);
      }
    __builtin_amdgcn_s_setprio(0);
    if (tt + 1 < S_NT) {
      if constexpr (F16B) {
        if (tt + 2 < S_NT) {
          asm volatile("s_waitcnt vmcnt(6)" ::: "memory");  // tile tt+1 landed
        } else {
          asm volatile("s_waitcnt vmcnt(0)" ::: "memory");
        }
      } else {
        asm volatile("s_waitcnt vmcnt(0) lgkmcnt(0)" ::: "memory");
      }
      __builtin_amdgcn_s_barrier();
      __builtin_amdgcn_sched_barrier(0);
    }
  }

  float* Cb = C + (long long)bz * TQ_ * TK_;
  #pragma unroll
  for (int i = 0; i < 4; ++i)
    #pragma unroll
    for (int j = 0; j < 4; ++j)
      #pragma unroll
      for (int rg = 0; rg < 4; ++rg) {
        int row = m0 + wr + i * 16 + qd * 4 + rg;
        int col = n0 + wc + j * 16 + ln;
        Cb[(long long)row * TK_ + col] = acc[i][j][rg];
      }
}

// ---------------------------------------------------------------------------
// Row softmax in place (+ optional f16 copy for ctx GEMM)
// ---------------------------------------------------------------------------
template<bool WP16>
__global__ __launch_bounds__(256) void softmax_kernel(
    float* __restrict__ P, _Float16* __restrict__ P16)
{
  __shared__ float red[8];
  float* p = P + (long long)blockIdx.x * TK_;
  const int t    = threadIdx.x;
  const int lane = t & 63;
  const int wave = t >> 6;

  float4 v[4];
  float mx = -3.0e38f;
  #pragma unroll
  for (int i = 0; i < 4; ++i) {
    v[i] = *(const float4*)&p[i * 1024 + t * 4];
    mx = fmaxf(mx, fmaxf(fmaxf(v[i].x, v[i].y), fmaxf(v[i].z, v[i].w)));
  }
  #pragma unroll
  for (int o = 32; o > 0; o >>= 1) mx = fmaxf(mx, __shfl_xor(mx, o, 64));
  if (lane == 0) red[wave] = mx;
  __syncthreads();
  mx = fmaxf(fmaxf(red[0], red[1]), fmaxf(red[2], red[3]));

  float s = 0.f;
  #pragma unroll
  for (int i = 0; i < 4; ++i) {
    v[i].x = __expf(v[i].x - mx);
    v[i].y = __expf(v[i].y - mx);
    v[i].z = __expf(v[i].z - mx);
    v[i].w = __expf(v[i].w - mx);
    s += (v[i].x + v[i].y) + (v[i].z + v[i].w);
  }
  #pragma unroll
  for (int o = 32; o > 0; o >>= 1) s += __shfl_xor(s, o, 64);
  if (lane == 0) red[4 + wave] = s;
  __syncthreads();
  s = (red[4] + red[5]) + (red[6] + red[7]);
  const float inv = 1.0f / s;

  _Float16* p16 = WP16 ? (P16 + (long long)blockIdx.x * TK_) : nullptr;
  #pragma unroll
  for (int i = 0; i < 4; ++i) {
    v[i].x *= inv; v[i].y *= inv; v[i].z *= inv; v[i].w *= inv;
    *(float4*)&p[i * 1024 + t * 4] = v[i];
    if constexpr (WP16) {
      union { _Float16 h[4]; uint2 u; } pk;
      pk.h[0] = (_Float16)v[i].x;
      pk.h[1] = (_Float16)v[i].y;
      pk.h[2] = (_Float16)v[i].z;
      pk.h[3] = (_Float16)v[i].w;
      *(uint2*)&p16[i * 1024 + t * 4] = pk.u;
    }
  }
}

// ---------------------------------------------------------------------------
// Context GEMM: C[b][q][d] = sum_k P[b,q,k] * encT[b,d,k]
// Tile 64x128, CBK=32, 256 thr (4 waves 2x2). 3-buffer counted-vmcnt
// pipeline, only 36 KB LDS -> 4 blocks/CU (16 waves, 50% occ).
// 3 glld/wave/stage (1 A + 2 B), vmcnt(3) == tile t+1 landed.
// Grid 1024, XCD-chunked, m-fastest decode.
// ---------------------------------------------------------------------------
#define CBM 64
#define CBN 128
#define CBK 32
#define C_NT (TK_ / CBK)   // 128

template<bool F16A>
__global__ __launch_bounds__(256) void gemm_ctx_kernel(
    const float* __restrict__ P, const _Float16* __restrict__ P16,
    const _Float16* __restrict__ ET, float* __restrict__ C)
{
  __shared__ _Float16 sA[3][CBM * CBK];   // 3 x 4 KB
  __shared__ _Float16 sB[3][CBN * CBK];   // 3 x 8 KB

  // 1024 blocks = 8 XCD chunks of 128; within a chunk m is fastest so the
  // 16 m-blocks sharing one encT panel co-reside on an XCD.
  const int bid = blockIdx.x;
  const int s   = (bid & 7) * 128 + (bid >> 3);
  const int m0  = (s & 15) * CBM;
  const int n0  = ((s >> 4) & 3) * CBN;
  const int bz  = s >> 6;

  const float*    Pb = P  + (long long)bz * TQ_ * TK_ + (long long)m0 * TK_;
  const _Float16* Eb = ET + (long long)bz * D_ * TK_  + (long long)n0 * TK_;

  const int t    = threadIdx.x;
  const int lane = t & 63;
  const int wave = t >> 6;        // 0..3
  const int wr   = (wave >> 1) * 32;   // 0,32
  const int wc   = (wave & 1) * 64;    // 0,64
  const int ln   = lane & 15;
  const int qd   = lane >> 4;
  const int sw   = qd ^ (ln & 3) ^ (ln >> 2);   // 4-slot swizzled k-slot

  f32x4 acc[2][4];
  #pragma unroll
  for (int i = 0; i < 2; ++i)
    #pragma unroll
    for (int j = 0; j < 4; ++j) { f32x4 z = {0.f,0.f,0.f,0.f}; acc[i][j] = z; }

  // staging: 1 KB chunk = 16 rows x 64 B; lane l -> row 16c+(l>>2),
  // global segment seg_src4(l), LDS linear dest = base + l*16.
  const int ab = seg_src4(lane) * 16;
  // B (encT): 8 chunks; wave handles {2w, 2w+1} -> rows 32w+(l>>2), +16
  const char* gB = (const char*)Eb + ((long long)(wave * 32 + (lane >> 2)) * TK_) * 2 + ab;
  const long long rstepB = (long long)16 * TK_ * 2;
  const int bdst = wave * 2048 + lane * 16;
  // A (P16): 4 chunks; wave handles chunk w -> rows 16w+(l>>2)
  const char* gA16 = nullptr;
  if constexpr (F16A) {
    const _Float16* Pb16 = P16 + (long long)bz * TQ_ * TK_ + (long long)m0 * TK_;
    gA16 = (const char*)Pb16 + ((long long)(wave * 16 + (lane >> 2)) * TK_) * 2 + ab;
  }
  const int adst = wave * 1024 + lane * 16;

  // A fallback: thread t -> row t>>2 (0..63), group t&3 (8 floats -> 16B slot)
  const int arowf = t >> 2;
  const int asegf = t & 3;
  const float* gAf = Pb + (long long)arowf * TK_ + asegf * 8;
  const int afoff = arowf * CBK + ((asegf ^ (arowf & 3) ^ ((arowf >> 2) & 3)) * 8);

  // 3 glld per call (F16A): 2 B + 1 A
  auto stage = [&](int buf, int k0) {
    const long long ko = (long long)k0 * 2;
    char* dB = (char*)sB[buf] + bdst;
    glld16(gB + ko, dB);
    glld16(gB + ko + rstepB, dB + 1024);
    if constexpr (F16A) {
      glld16(gA16 + ko, (char*)sA[buf] + adst);
    } else {
      float4 v0 = *(const float4*)(gAf + k0);
      float4 v1 = *(const float4*)(gAf + k0 + 4);
      __align__(16) _Float16 hb[8];
      hb[0] = (_Float16)v0.x; hb[1] = (_Float16)v0.y;
      hb[2] = (_Float16)v0.z; hb[3] = (_Float16)v0.w;
      hb[4] = (_Float16)v1.x; hb[5] = (_Float16)v1.y;
      hb[6] = (_Float16)v1.z; hb[7] = (_Float16)v1.w;
      *(uint4*)&sA[buf][afoff] = *(const uint4*)hb;
    }
  };

  stage(0, 0);
  stage(1, CBK);
  if constexpr (F16A) {
    asm volatile("s_waitcnt vmcnt(3)" ::: "memory");     // tile0's 3 done
  } else {
    asm volatile("s_waitcnt vmcnt(0) lgkmcnt(0)" ::: "memory");
  }
  __builtin_amdgcn_s_barrier();
  __builtin_amdgcn_sched_barrier(0);

  int cur = 0, nxt = 2;
  #pragma unroll 1
  for (int tt = 0; tt < C_NT; ++tt) {
    if (tt + 2 < C_NT) stage(nxt, (tt + 2) * CBK);

    const _Float16* bA  = sA[cur];
    const _Float16* bBv = sB[cur];
    f16x8 fa[2], fb[4];
    #pragma unroll
    for (int i = 0; i < 2; ++i)
      fa[i] = *(const f16x8*)&bA[(wr + i * 16 + ln) * CBK + sw * 8];
    #pragma unroll
    for (int j = 0; j < 4; ++j)
      fb[j] = *(const f16x8*)&bBv[(wc + j * 16 + ln) * CBK + sw * 8];
    __builtin_amdgcn_s_setprio(1);
    #pragma unroll
    for (int i = 0; i < 2; ++i)
      #pragma unroll
      for (int j = 0; j < 4; ++j)
        acc[i][j] = __builtin_amdgcn_mfma_f32_16x16x32_f16(fa[i], fb[j], acc[i][j], 0, 0, 0);
    __builtin_amdgcn_s_setprio(0);
    if (tt + 1 < C_NT) {
      if constexpr (F16A) {
        if (tt + 2 < C_NT) {
          asm volatile("s_waitcnt vmcnt(3)" ::: "memory");  // tile tt+1 landed
        } else {
          asm volatile("s_waitcnt vmcnt(0)" ::: "memory");
        }
      } else {
        asm volatile("s_waitcnt vmcnt(0) lgkmcnt(0)" ::: "memory");
      }
      __builtin_amdgcn_s_barrier();
      __builtin_amdgcn_sched_barrier(0);
    }
    cur = (cur == 2) ? 0 : cur + 1;
    nxt = (nxt == 2) ? 0 : nxt + 1;
  }

  float* Cb = C + (long long)bz * TQ_ * D_;
  #pragma unroll
  for (int i = 0; i < 2; ++i)
    #pragma unroll
    for (int j = 0; j < 4; ++j)
      #pragma unroll
      for (int rg = 0; rg < 4; ++rg) {
        int row = m0 + wr + i * 16 + qd * 4 + rg;
        int col = n0 + wc + j * 16 + ln;
        Cb[(long long)row * D_ + col] = acc[i][j][rg];
      }
}

// ---------------------------------------------------------------------------
extern "C" void kernel_launch(void* const* d_in, const int* in_sizes, int n_in,
                              void* d_out, int out_size, void* d_ws, size_t ws_size,
                              hipStream_t stream) {
  (void)in_sizes; (void)n_in; (void)out_size;
  const float* dec = (const float*)d_in[0];   // [16,1024,512]
  const float* enc = (const float*)d_in[1];   // [16,4096,512]
  const float* Wa  = (const float*)d_in[2];   // [512,512]
  // b_a constant along softmax axis -> cancels exactly; unused.

  float* ctx   = (float*)d_out;                                   // [16,1024,512]
  float* align = ctx + (long long)B_ * TQ_ * D_;                  // [16,1024,4096]

  char* ws = (char*)d_ws;
  const size_t SZ_ENCT = (size_t)B_ * D_ * TK_ * 2;   // 67,108,864
  const size_t SZ_DEC2 = (size_t)B_ * TQ_ * D_ * 2;   // 16,777,216
  const size_t SZ_ENCF = (size_t)B_ * TK_ * D_ * 2;   // 67,108,864
  const size_t SZ_P16  = (size_t)B_ * TQ_ * TK_ * 2;  // 134,217,728

  _Float16* encT  = (_Float16*)(ws);
  _Float16* dec2h = (_Float16*)(ws + SZ_ENCT);
  _Float16* dec2l = (_Float16*)(ws + SZ_ENCT + SZ_DEC2);
  _Float16* encF  = (_Float16*)(ws + SZ_ENCT + 2 * SZ_DEC2);
  // P16 overlays dec2h/dec2l/encF -- all dead once score finishes (stream order)
  _Float16* p16   = (_Float16*)(ws + SZ_ENCT);

  const bool mid  = ws_size >= SZ_ENCT + 2 * SZ_DEC2 + SZ_ENCF;  // 167.8 MB
  const bool full = ws_size >= SZ_ENCT + SZ_P16;                  // 201.3 MB

  // 1) encT[b][d][k] = f16(enc[b][k][d]); also encF16[b][k][d] if room
  transpose_conv_kernel<<<dim3(TK_ / 64, D_ / 64, B_), 256, 0, stream>>>(
      enc, encT, mid ? encF : nullptr);

  // 2) dec2 = dec @ W^T (split-bf16 triple), epilogue -> f16 hi/lo planes
  gemm_dec2_kernel<<<dim3(D_ / DBN, (B_ * TQ_) / DBM, 1), 256, 0, stream>>>(
      dec, Wa, dec2h, dec2l);

  // 3) score = dec2 @ enc^T (f16: Ah*B + Al*B)
  if (mid)
    gemm_score_kernel<true><<<dim3(TK_ / SBN, TQ_ / SBM, B_), 256, 0, stream>>>(
        dec2h, dec2l, enc, encF, align);
  else
    gemm_score_kernel<false><<<dim3(TK_ / SBN, TQ_ / SBM, B_), 256, 0, stream>>>(
        dec2h, dec2l, enc, nullptr, align);

  // 4) softmax rows in place (+ f16 copy if room)
  if (full)
    softmax_kernel<true><<<B_ * TQ_, 256, 0, stream>>>(align, p16);
  else
    softmax_kernel<false><<<B_ * TQ_, 256, 0, stream>>>(align, nullptr);

  // 5) ctx = P @ encT^T (f16), 1-D grid with XCD chunk swizzle
  if (full)
    gemm_ctx_kernel<true><<<dim3((TQ_ / CBM) * (D_ / CBN) * B_), 256, 0, stream>>>(
        align, p16, encT, ctx);
  else
    gemm_ctx_kernel<false><<<dim3((TQ_ / CBM) * (D_ / CBN) * B_), 256, 0, stream>>>(
        align, nullptr, encT, ctx);
}

// Round 5
// 852.977 us; speedup vs baseline: 1.0927x; 1.0185x over previous
//
#include <hip/hip_runtime.h>
#include <hip/hip_bf16.h>

#define B_  16
#define TQ_ 1024
#define TK_ 4096
#define D_  512

typedef unsigned short u16;
typedef __attribute__((ext_vector_type(8))) short short8;      // 8 bf16
typedef __attribute__((ext_vector_type(8))) _Float16 f16x8;    // 8 f16 (4 VGPRs)
typedef __attribute__((ext_vector_type(4))) float f32x4;

__device__ __forceinline__ u16 bf16_rne(float x) {
  unsigned u = __float_as_uint(x);
  u += 0x7FFFu + ((u >> 16) & 1u);
  return (u16)(u >> 16);
}
__device__ __forceinline__ float bf16_as_f32(u16 h) {
  return __uint_as_float(((unsigned)h) << 16);
}
__device__ __forceinline__ void split_bf16(float x, u16& h, u16& l) {
  u16 hh = bf16_rne(x);
  h = hh;
  l = bf16_rne(x - bf16_as_f32(hh));
}

// async global->LDS, 16B per lane; LDS dest must be wave-contiguous (base + lane*16)
__device__ __forceinline__ void glld16(const void* g, void* lds) {
  __builtin_amdgcn_global_load_lds(
      (const __attribute__((address_space(1))) unsigned int*)g,
      (__attribute__((address_space(3))) unsigned int*)lds, 16, 0, 0);
}

// 4-slot swizzle (64B rows, BK=32): LDS slot (row,s) holds global segment
// s ^ (row&3) ^ ((row>>2)&3). Staging lane l fetches segment seg_src4(l);
// reads use slot qd ^ (ln&3) ^ (ln>>2). Max 2-way aliasing (free, m136).
__device__ __forceinline__ int seg_src4(int l) {
  return (l & 3) ^ ((l >> 2) & 3) ^ ((l >> 4) & 3);
}

// ---------------------------------------------------------------------------
// x fp32 -> hi/lo bf16 planes (vectorized, 8 elems/thread)
// ---------------------------------------------------------------------------
__global__ __launch_bounds__(256) void split_planes_kernel(
    const float* __restrict__ X, u16* __restrict__ H, u16* __restrict__ L,
    int n8)
{
  int i = blockIdx.x * 256 + threadIdx.x;
  if (i >= n8) return;
  const float4* src = (const float4*)X + (size_t)i * 2;
  float4 a = src[0], b = src[1];
  __align__(16) u16 h[8], l[8];
  split_bf16(a.x, h[0], l[0]);
  split_bf16(a.y, h[1], l[1]);
  split_bf16(a.z, h[2], l[2]);
  split_bf16(a.w, h[3], l[3]);
  split_bf16(b.x, h[4], l[4]);
  split_bf16(b.y, h[5], l[5]);
  split_bf16(b.z, h[6], l[6]);
  split_bf16(b.w, h[7], l[7]);
  *(uint4*)&H[(size_t)i * 8] = *(const uint4*)h;
  *(uint4*)&L[(size_t)i * 8] = *(const uint4*)l;
}

// ---------------------------------------------------------------------------
// enc [b][k][d] fp32 -> encT [b][d][k] f16  (+ optional encF16 [b][k][d] f16)
// ---------------------------------------------------------------------------
__global__ __launch_bounds__(256) void transpose_conv_kernel(
    const float* __restrict__ E, _Float16* __restrict__ ET,
    _Float16* __restrict__ EF)
{
  __shared__ float tile[64][65];
  const int b  = blockIdx.z;
  const int k0 = blockIdx.x * 64;
  const int d0 = blockIdx.y * 64;
  const float* Eb = E + (long long)b * TK_ * D_;
  _Float16* ETb = ET + (long long)b * D_ * TK_;

  const int t  = threadIdx.x;
  const int r  = t >> 2;          // 0..63
  const int c4 = (t & 3) * 16;    // 0,16,32,48

  __align__(16) _Float16 g[16];
  #pragma unroll
  for (int i = 0; i < 16; i += 4) {
    float4 v = *(const float4*)&Eb[(long long)(k0 + r) * D_ + d0 + c4 + i];
    tile[r][c4 + i + 0] = v.x;
    tile[r][c4 + i + 1] = v.y;
    tile[r][c4 + i + 2] = v.z;
    tile[r][c4 + i + 3] = v.w;
    g[i + 0] = (_Float16)v.x;
    g[i + 1] = (_Float16)v.y;
    g[i + 2] = (_Float16)v.z;
    g[i + 3] = (_Float16)v.w;
  }
  if (EF) {
    _Float16* EFb = EF + (long long)b * TK_ * D_;
    uint4* dstF = (uint4*)&EFb[(long long)(k0 + r) * D_ + d0 + c4];
    dstF[0] = ((const uint4*)g)[0];
    dstF[1] = ((const uint4*)g)[1];
  }
  __syncthreads();

  __align__(16) _Float16 h[16];
  #pragma unroll
  for (int i = 0; i < 16; ++i) h[i] = (_Float16)tile[c4 + i][r];
  uint4* dst = (uint4*)&ETb[(long long)(d0 + r) * TK_ + k0 + c4];
  dst[0] = ((const uint4*)h)[0];
  dst[1] = ((const uint4*)h)[1];
}

// ---------------------------------------------------------------------------
// dec2 = dec @ W^T  -- PRESPLIT path: A,B are bf16 hi/lo planes, all staging
// via glld16 (no VALU). Tile 64x128, BK=32, 256 thr (4 waves 2x2), 24 KB LDS
// single-buffer (R1-proven structure), grid 1024 blocks (4/CU).
// ---------------------------------------------------------------------------
#define D2BM 64
#define D2BN 128
#define D2BK 32

__global__ __launch_bounds__(256) void gemm_dec2p_kernel(
    const u16* __restrict__ Ahp, const u16* __restrict__ Alp,
    const u16* __restrict__ Bhp, const u16* __restrict__ Blp,
    _Float16* __restrict__ Ch, _Float16* __restrict__ Cl)
{
  __shared__ u16 sAh[D2BM * D2BK];   // 4 KB
  __shared__ u16 sAl[D2BM * D2BK];   // 4 KB
  __shared__ u16 sBh[D2BN * D2BK];   // 8 KB
  __shared__ u16 sBl[D2BN * D2BK];   // 8 KB

  const int m0 = blockIdx.y * D2BM;
  const int n0 = blockIdx.x * D2BN;

  const int t    = threadIdx.x;
  const int lane = t & 63;
  const int wave = t >> 6;             // 0..3
  const int wrm  = (wave >> 1) * 32;   // 0,32
  const int wcn  = (wave & 1) * 64;    // 0,64
  const int ln   = lane & 15;
  const int qd   = lane >> 4;
  const int sw   = qd ^ (ln & 3) ^ (ln >> 2);

  f32x4 acc[2][4];
  #pragma unroll
  for (int i = 0; i < 2; ++i)
    #pragma unroll
    for (int j = 0; j < 4; ++j) { f32x4 z = {0.f,0.f,0.f,0.f}; acc[i][j] = z; }

  const int ab = seg_src4(lane) * 16;
  // A: 4 chunks of 1 KB; wave handles chunk `wave`: rows 16w+(l>>2)
  const char* gAh = (const char*)Ahp + (long long)(m0 + wave * 16 + (lane >> 2)) * D_ * 2 + ab;
  const char* gAl = (const char*)Alp + (long long)(m0 + wave * 16 + (lane >> 2)) * D_ * 2 + ab;
  const int adst = wave * 1024 + lane * 16;
  // B: 8 chunks; wave handles {2w,2w+1}: rows 32w+(l>>2), +16
  const char* gBh = (const char*)Bhp + (long long)(n0 + wave * 32 + (lane >> 2)) * D_ * 2 + ab;
  const char* gBl = (const char*)Blp + (long long)(n0 + wave * 32 + (lane >> 2)) * D_ * 2 + ab;
  const long long rstep = (long long)16 * D_ * 2;
  const int bdst = wave * 2048 + lane * 16;

  for (int k0 = 0; k0 < D_; k0 += D2BK) {
    const long long ko = (long long)k0 * 2;
    glld16(gAh + ko, (char*)sAh + adst);
    glld16(gAl + ko, (char*)sAl + adst);
    glld16(gBh + ko, (char*)sBh + bdst);
    glld16(gBh + ko + rstep, (char*)sBh + bdst + 1024);
    glld16(gBl + ko, (char*)sBl + bdst);
    glld16(gBl + ko + rstep, (char*)sBl + bdst + 1024);
    __syncthreads();

    short8 fah[2], fal[2], fbh[4], fbl[4];
    #pragma unroll
    for (int i = 0; i < 2; ++i) {
      const int ra = (wrm + i * 16 + ln) * D2BK + sw * 8;
      fah[i] = *(const short8*)&sAh[ra];
      fal[i] = *(const short8*)&sAl[ra];
    }
    #pragma unroll
    for (int j = 0; j < 4; ++j) {
      const int rb = (wcn + j * 16 + ln) * D2BK + sw * 8;
      fbh[j] = *(const short8*)&sBh[rb];
      fbl[j] = *(const short8*)&sBl[rb];
    }
    #pragma unroll
    for (int i = 0; i < 2; ++i)
      #pragma unroll
      for (int j = 0; j < 4; ++j) {
        acc[i][j] = __builtin_amdgcn_mfma_f32_16x16x32_bf16(fah[i], fbh[j], acc[i][j], 0, 0, 0);
        acc[i][j] = __builtin_amdgcn_mfma_f32_16x16x32_bf16(fah[i], fbl[j], acc[i][j], 0, 0, 0);
        acc[i][j] = __builtin_amdgcn_mfma_f32_16x16x32_bf16(fal[i], fbh[j], acc[i][j], 0, 0, 0);
      }
    __syncthreads();
  }

  #pragma unroll
  for (int i = 0; i < 2; ++i)
    #pragma unroll
    for (int j = 0; j < 4; ++j)
      #pragma unroll
      for (int rg = 0; rg < 4; ++rg) {
        int row = m0 + wrm + i * 16 + qd * 4 + rg;
        int col = n0 + wcn + j * 16 + ln;
        float x = acc[i][j][rg];
        _Float16 h = (_Float16)x;
        _Float16 l = (_Float16)(x - (float)h);
        long long idx = (long long)row * D_ + col;
        Ch[idx] = h;
        Cl[idx] = l;
      }
}

// ---------------------------------------------------------------------------
// dec2 fallback (in-kernel split): original split-bf16 triple
// ---------------------------------------------------------------------------
#define DBM 128
#define DBN 128
#define DBK 32
#define DPAD 40

__global__ __launch_bounds__(256) void gemm_dec2_kernel(
    const float* __restrict__ A, const float* __restrict__ Bm,
    _Float16* __restrict__ Ch, _Float16* __restrict__ Cl)
{
  __shared__ u16 Ah[DBM * DPAD];
  __shared__ u16 Al[DBM * DPAD];
  __shared__ u16 Bh[DBN * DPAD];
  __shared__ u16 Bl[DBN * DPAD];

  const float* Ab = A  + (long long)(blockIdx.y * DBM) * D_;
  const float* Bb = Bm + (long long)(blockIdx.x * DBN) * D_;

  const int t    = threadIdx.x;
  const int r    = t >> 1;
  const int hf   = t & 1;
  const int lane = t & 63;
  const int wave = t >> 6;
  const int wr   = (wave >> 1) * 64;
  const int wc   = (wave & 1) * 64;
  const int ln   = lane & 15;
  const int qd   = lane >> 4;

  f32x4 acc[4][4];
  #pragma unroll
  for (int i = 0; i < 4; ++i)
    #pragma unroll
    for (int j = 0; j < 4; ++j) { f32x4 z = {0.f,0.f,0.f,0.f}; acc[i][j] = z; }

  const float* srcA = Ab + (long long)r * D_ + hf * 16;
  const float* srcB = Bb + (long long)r * D_ + hf * 16;
  u16* dAh = &Ah[r * DPAD + hf * 16];
  u16* dAl = &Al[r * DPAD + hf * 16];
  u16* dBh = &Bh[r * DPAD + hf * 16];
  u16* dBl = &Bl[r * DPAD + hf * 16];

  for (int k0 = 0; k0 < D_; k0 += DBK) {
    {
      __align__(16) u16 h[16], l[16];
      #pragma unroll
      for (int i = 0; i < 16; i += 4) {
        float4 v = *(const float4*)(srcA + k0 + i);
        split_bf16(v.x, h[i+0], l[i+0]);
        split_bf16(v.y, h[i+1], l[i+1]);
        split_bf16(v.z, h[i+2], l[i+2]);
        split_bf16(v.w, h[i+3], l[i+3]);
      }
      ((uint4*)dAh)[0] = ((const uint4*)h)[0];
      ((uint4*)dAh)[1] = ((const uint4*)h)[1];
      ((uint4*)dAl)[0] = ((const uint4*)l)[0];
      ((uint4*)dAl)[1] = ((const uint4*)l)[1];
      #pragma unroll
      for (int i = 0; i < 16; i += 4) {
        float4 v = *(const float4*)(srcB + k0 + i);
        split_bf16(v.x, h[i+0], l[i+0]);
        split_bf16(v.y, h[i+1], l[i+1]);
        split_bf16(v.z, h[i+2], l[i+2]);
        split_bf16(v.w, h[i+3], l[i+3]);
      }
      ((uint4*)dBh)[0] = ((const uint4*)h)[0];
      ((uint4*)dBh)[1] = ((const uint4*)h)[1];
      ((uint4*)dBl)[0] = ((const uint4*)l)[0];
      ((uint4*)dBl)[1] = ((const uint4*)l)[1];
    }
    __syncthreads();

    short8 fah[4], fal[4], fbh[4], fbl[4];
    #pragma unroll
    for (int i = 0; i < 4; ++i) {
      int ra = (wr + i * 16 + ln) * DPAD + qd * 8;
      int rb = (wc + i * 16 + ln) * DPAD + qd * 8;
      fah[i] = *(const short8*)&Ah[ra];
      fal[i] = *(const short8*)&Al[ra];
      fbh[i] = *(const short8*)&Bh[rb];
      fbl[i] = *(const short8*)&Bl[rb];
    }
    #pragma unroll
    for (int i = 0; i < 4; ++i)
      #pragma unroll
      for (int j = 0; j < 4; ++j) {
        acc[i][j] = __builtin_amdgcn_mfma_f32_16x16x32_bf16(fah[i], fbh[j], acc[i][j], 0, 0, 0);
        acc[i][j] = __builtin_amdgcn_mfma_f32_16x16x32_bf16(fah[i], fbl[j], acc[i][j], 0, 0, 0);
        acc[i][j] = __builtin_amdgcn_mfma_f32_16x16x32_bf16(fal[i], fbh[j], acc[i][j], 0, 0, 0);
      }
    __syncthreads();
  }

  const int m0 = blockIdx.y * DBM;
  const int n0 = blockIdx.x * DBN;
  #pragma unroll
  for (int i = 0; i < 4; ++i)
    #pragma unroll
    for (int j = 0; j < 4; ++j)
      #pragma unroll
      for (int rg = 0; rg < 4; ++rg) {
        int row = m0 + wr + i * 16 + qd * 4 + rg;
        int col = n0 + wc + j * 16 + ln;
        float x = acc[i][j][rg];
        _Float16 h = (_Float16)x;
        _Float16 l = (_Float16)(x - (float)h);
        long long idx = (long long)row * D_ + col;
        Ch[idx] = h;
        Cl[idx] = l;
      }
}

// ---------------------------------------------------------------------------
// Score GEMM: C[b][q][k] = sum_d dec2[b,q,d] * enc[b,k,d]
// R1-proven structure: single 24 KB buffer, stage -> sync -> compute -> sync.
// A planes + B (encF16) via glld, XOR-swizzled tiles.
// ---------------------------------------------------------------------------
#define SBM 128
#define SBN 128
#define SBK 32

template<bool F16B>
__global__ __launch_bounds__(256) void gemm_score_kernel(
    const _Float16* __restrict__ A_h, const _Float16* __restrict__ A_l,
    const float* __restrict__ Bf, const _Float16* __restrict__ B16,
    float* __restrict__ C)
{
  __shared__ _Float16 sAh[SBM * SBK];   // 8 KB, glld-staged, swizzled layout
  __shared__ _Float16 sAl[SBM * SBK];   // 8 KB
  __shared__ _Float16 sB [SBN * SBK];   // 8 KB

  const int bz = blockIdx.z;
  const int m0 = blockIdx.y * SBM;
  const int n0 = blockIdx.x * SBN;
  const _Float16* Ahb = A_h + (long long)bz * TQ_ * D_ + (long long)m0 * D_;
  const _Float16* Alb = A_l + (long long)bz * TQ_ * D_ + (long long)m0 * D_;

  const int t    = threadIdx.x;
  const int lane = t & 63;
  const int wave = t >> 6;
  const int wr   = (wave >> 1) * 64;
  const int wc   = (wave & 1) * 64;
  const int ln   = lane & 15;
  const int qd   = lane >> 4;
  const int sw   = qd ^ (ln & 3) ^ (ln >> 2);   // swizzled k-slot for reads

  f32x4 acc[4][4];
  #pragma unroll
  for (int i = 0; i < 4; ++i)
    #pragma unroll
    for (int j = 0; j < 4; ++j) { f32x4 z = {0.f,0.f,0.f,0.f}; acc[i][j] = z; }

  // glld mapping: wave handles chunks {2w, 2w+1} of each plane; lane l ->
  // row 16c + (l>>2), global segment seg_src4(l) (swizzle), LDS = base + l*16.
  const int c0   = wave * 2;
  const int arow = c0 * 16 + (lane >> 2);
  const int ab   = seg_src4(lane) * 16;
  const char* gAh = (const char*)Ahb + (long long)arow * D_ * 2 + ab;
  const char* gAl = (const char*)Alb + (long long)arow * D_ * 2 + ab;
  const long long rstep = (long long)16 * D_ * 2;   // +16 rows
  char* lAh = (char*)sAh + c0 * 1024 + lane * 16;
  char* lAl = (char*)sAl + c0 * 1024 + lane * 16;
  char* lB  = (char*)sB  + c0 * 1024 + lane * 16;

  const char* gB16 = nullptr;
  if constexpr (F16B) {
    const _Float16* Bb16 = B16 + (long long)bz * TK_ * D_ + (long long)n0 * D_;
    gB16 = (const char*)Bb16 + (long long)arow * D_ * 2 + ab;
  }

  // fallback B staging: thread t -> row t>>1, half t&1; swizzled store slots
  const float* Bb = Bf + (long long)bz * TK_ * D_ + (long long)n0 * D_;
  const int brow = t >> 1;
  const int bhf  = t & 1;
  const float* srcB = Bb + (long long)brow * D_ + bhf * 16;
  const int bh2 = (brow & 3) ^ ((brow >> 2) & 3);
  _Float16* dB0 = &sB[brow * SBK + ((2 * bhf    ) ^ bh2) * 8];
  _Float16* dB1 = &sB[brow * SBK + ((2 * bhf + 1) ^ bh2) * 8];

  for (int k0 = 0; k0 < D_; k0 += SBK) {
    glld16(gAh + (long long)k0 * 2, lAh);
    glld16(gAh + (long long)k0 * 2 + rstep, lAh + 1024);
    glld16(gAl + (long long)k0 * 2, lAl);
    glld16(gAl + (long long)k0 * 2 + rstep, lAl + 1024);
    if constexpr (F16B) {
      glld16(gB16 + (long long)k0 * 2, lB);
      glld16(gB16 + (long long)k0 * 2 + rstep, lB + 1024);
    } else {
      __align__(16) _Float16 hb[16];
      #pragma unroll
      for (int i = 0; i < 16; i += 4) {
        float4 v = *(const float4*)(srcB + k0 + i);
        hb[i+0] = (_Float16)v.x;
        hb[i+1] = (_Float16)v.y;
        hb[i+2] = (_Float16)v.z;
        hb[i+3] = (_Float16)v.w;
      }
      *(uint4*)dB0 = ((const uint4*)hb)[0];
      *(uint4*)dB1 = ((const uint4*)hb)[1];
    }
    __syncthreads();

    f16x8 fah[4], fal[4], fb[4];
    #pragma unroll
    for (int i = 0; i < 4; ++i) {
      int ra = (wr + i * 16 + ln) * SBK + sw * 8;
      int rb = (wc + i * 16 + ln) * SBK + sw * 8;
      fah[i] = *(const f16x8*)&sAh[ra];
      fal[i] = *(const f16x8*)&sAl[ra];
      fb[i]  = *(const f16x8*)&sB[rb];
    }
    #pragma unroll
    for (int i = 0; i < 4; ++i)
      #pragma unroll
      for (int j = 0; j < 4; ++j) {
        acc[i][j] = __builtin_amdgcn_mfma_f32_16x16x32_f16(fah[i], fb[j], acc[i][j], 0, 0, 0);
        acc[i][j] = __builtin_amdgcn_mfma_f32_16x16x32_f16(fal[i], fb[j], acc[i][j], 0, 0, 0);
      }
    __syncthreads();
  }

  float* Cb = C + (long long)bz * TQ_ * TK_;
  #pragma unroll
  for (int i = 0; i < 4; ++i)
    #pragma unroll
    for (int j = 0; j < 4; ++j)
      #pragma unroll
      for (int rg = 0; rg < 4; ++rg) {
        int row = m0 + wr + i * 16 + qd * 4 + rg;
        int col = n0 + wc + j * 16 + ln;
        Cb[(long long)row * TK_ + col] = acc[i][j][rg];
      }
}

// ---------------------------------------------------------------------------
// Row softmax in place (+ optional f16 copy for ctx GEMM)
// ---------------------------------------------------------------------------
template<bool WP16>
__global__ __launch_bounds__(256) void softmax_kernel(
    float* __restrict__ P, _Float16* __restrict__ P16)
{
  __shared__ float red[8];
  float* p = P + (long long)blockIdx.x * TK_;
  const int t    = threadIdx.x;
  const int lane = t & 63;
  const int wave = t >> 6;

  float4 v[4];
  float mx = -3.0e38f;
  #pragma unroll
  for (int i = 0; i < 4; ++i) {
    v[i] = *(const float4*)&p[i * 1024 + t * 4];
    mx = fmaxf(mx, fmaxf(fmaxf(v[i].x, v[i].y), fmaxf(v[i].z, v[i].w)));
  }
  #pragma unroll
  for (int o = 32; o > 0; o >>= 1) mx = fmaxf(mx, __shfl_xor(mx, o, 64));
  if (lane == 0) red[wave] = mx;
  __syncthreads();
  mx = fmaxf(fmaxf(red[0], red[1]), fmaxf(red[2], red[3]));

  float s = 0.f;
  #pragma unroll
  for (int i = 0; i < 4; ++i) {
    v[i].x = __expf(v[i].x - mx);
    v[i].y = __expf(v[i].y - mx);
    v[i].z = __expf(v[i].z - mx);
    v[i].w = __expf(v[i].w - mx);
    s += (v[i].x + v[i].y) + (v[i].z + v[i].w);
  }
  #pragma unroll
  for (int o = 32; o > 0; o >>= 1) s += __shfl_xor(s, o, 64);
  if (lane == 0) red[4 + wave] = s;
  __syncthreads();
  s = (red[4] + red[5]) + (red[6] + red[7]);
  const float inv = 1.0f / s;

  _Float16* p16 = WP16 ? (P16 + (long long)blockIdx.x * TK_) : nullptr;
  #pragma unroll
  for (int i = 0; i < 4; ++i) {
    v[i].x *= inv; v[i].y *= inv; v[i].z *= inv; v[i].w *= inv;
    *(float4*)&p[i * 1024 + t * 4] = v[i];
    if constexpr (WP16) {
      union { _Float16 h[4]; uint2 u; } pk;
      pk.h[0] = (_Float16)v[i].x;
      pk.h[1] = (_Float16)v[i].y;
      pk.h[2] = (_Float16)v[i].z;
      pk.h[3] = (_Float16)v[i].w;
      *(uint2*)&p16[i * 1024 + t * 4] = pk.u;
    }
  }
}

// ---------------------------------------------------------------------------
// Context GEMM: C[b][q][d] = sum_k P[b,q,k] * encT[b,d,k]
// Tile 64x128, CBK=32, 256 thr (4 waves 2x2). 3-buffer counted-vmcnt
// pipeline, 36 KB LDS -> 4 blocks/CU. 3 glld/wave/stage, vmcnt(3).
// Grid 1024, XCD-chunked, m-fastest decode.
// ---------------------------------------------------------------------------
#define CBM 64
#define CBN 128
#define CBK 32
#define C_NT (TK_ / CBK)   // 128

template<bool F16A>
__global__ __launch_bounds__(256) void gemm_ctx_kernel(
    const float* __restrict__ P, const _Float16* __restrict__ P16,
    const _Float16* __restrict__ ET, float* __restrict__ C)
{
  __shared__ _Float16 sA[3][CBM * CBK];   // 3 x 4 KB
  __shared__ _Float16 sB[3][CBN * CBK];   // 3 x 8 KB

  const int bid = blockIdx.x;
  const int s   = (bid & 7) * 128 + (bid >> 3);
  const int m0  = (s & 15) * CBM;
  const int n0  = ((s >> 4) & 3) * CBN;
  const int bz  = s >> 6;

  const float*    Pb = P  + (long long)bz * TQ_ * TK_ + (long long)m0 * TK_;
  const _Float16* Eb = ET + (long long)bz * D_ * TK_  + (long long)n0 * TK_;

  const int t    = threadIdx.x;
  const int lane = t & 63;
  const int wave = t >> 6;        // 0..3
  const int wr   = (wave >> 1) * 32;   // 0,32
  const int wc   = (wave & 1) * 64;    // 0,64
  const int ln   = lane & 15;
  const int qd   = lane >> 4;
  const int sw   = qd ^ (ln & 3) ^ (ln >> 2);   // 4-slot swizzled k-slot

  f32x4 acc[2][4];
  #pragma unroll
  for (int i = 0; i < 2; ++i)
    #pragma unroll
    for (int j = 0; j < 4; ++j) { f32x4 z = {0.f,0.f,0.f,0.f}; acc[i][j] = z; }

  const int ab = seg_src4(lane) * 16;
  const char* gB = (const char*)Eb + ((long long)(wave * 32 + (lane >> 2)) * TK_) * 2 + ab;
  const long long rstepB = (long long)16 * TK_ * 2;
  const int bdst = wave * 2048 + lane * 16;
  const char* gA16 = nullptr;
  if constexpr (F16A) {
    const _Float16* Pb16 = P16 + (long long)bz * TQ_ * TK_ + (long long)m0 * TK_;
    gA16 = (const char*)Pb16 + ((long long)(wave * 16 + (lane >> 2)) * TK_) * 2 + ab;
  }
  const int adst = wave * 1024 + lane * 16;

  const int arowf = t >> 2;
  const int asegf = t & 3;
  const float* gAf = Pb + (long long)arowf * TK_ + asegf * 8;
  const int afoff = arowf * CBK + ((asegf ^ (arowf & 3) ^ ((arowf >> 2) & 3)) * 8);

  auto stage = [&](int buf, int k0) {
    const long long ko = (long long)k0 * 2;
    char* dB = (char*)sB[buf] + bdst;
    glld16(gB + ko, dB);
    glld16(gB + ko + rstepB, dB + 1024);
    if constexpr (F16A) {
      glld16(gA16 + ko, (char*)sA[buf] + adst);
    } else {
      float4 v0 = *(const float4*)(gAf + k0);
      float4 v1 = *(const float4*)(gAf + k0 + 4);
      __align__(16) _Float16 hb[8];
      hb[0] = (_Float16)v0.x; hb[1] = (_Float16)v0.y;
      hb[2] = (_Float16)v0.z; hb[3] = (_Float16)v0.w;
      hb[4] = (_Float16)v1.x; hb[5] = (_Float16)v1.y;
      hb[6] = (_Float16)v1.z; hb[7] = (_Float16)v1.w;
      *(uint4*)&sA[buf][afoff] = *(const uint4*)hb;
    }
  };

  stage(0, 0);
  stage(1, CBK);
  if constexpr (F16A) {
    asm volatile("s_waitcnt vmcnt(3)" ::: "memory");     // tile0's 3 done
  } else {
    asm volatile("s_waitcnt vmcnt(0) lgkmcnt(0)" ::: "memory");
  }
  __builtin_amdgcn_s_barrier();
  __builtin_amdgcn_sched_barrier(0);

  int cur = 0, nxt = 2;
  #pragma unroll 1
  for (int tt = 0; tt < C_NT; ++tt) {
    if (tt + 2 < C_NT) stage(nxt, (tt + 2) * CBK);

    const _Float16* bA  = sA[cur];
    const _Float16* bBv = sB[cur];
    f16x8 fa[2], fb[4];
    #pragma unroll
    for (int i = 0; i < 2; ++i)
      fa[i] = *(const f16x8*)&bA[(wr + i * 16 + ln) * CBK + sw * 8];
    #pragma unroll
    for (int j = 0; j < 4; ++j)
      fb[j] = *(const f16x8*)&bBv[(wc + j * 16 + ln) * CBK + sw * 8];
    __builtin_amdgcn_s_setprio(1);
    #pragma unroll
    for (int i = 0; i < 2; ++i)
      #pragma unroll
      for (int j = 0; j < 4; ++j)
        acc[i][j] = __builtin_amdgcn_mfma_f32_16x16x32_f16(fa[i], fb[j], acc[i][j], 0, 0, 0);
    __builtin_amdgcn_s_setprio(0);
    if (tt + 1 < C_NT) {
      if constexpr (F16A) {
        if (tt + 2 < C_NT) {
          asm volatile("s_waitcnt vmcnt(3)" ::: "memory");  // tile tt+1 landed
        } else {
          asm volatile("s_waitcnt vmcnt(0)" ::: "memory");
        }
      } else {
        asm volatile("s_waitcnt vmcnt(0) lgkmcnt(0)" ::: "memory");
      }
      __builtin_amdgcn_s_barrier();
      __builtin_amdgcn_sched_barrier(0);
    }
    cur = (cur == 2) ? 0 : cur + 1;
    nxt = (nxt == 2) ? 0 : nxt + 1;
  }

  float* Cb = C + (long long)bz * TQ_ * D_;
  #pragma unroll
  for (int i = 0; i < 2; ++i)
    #pragma unroll
    for (int j = 0; j < 4; ++j)
      #pragma unroll
      for (int rg = 0; rg < 4; ++rg) {
        int row = m0 + wr + i * 16 + qd * 4 + rg;
        int col = n0 + wc + j * 16 + ln;
        Cb[(long long)row * D_ + col] = acc[i][j][rg];
      }
}

// ---------------------------------------------------------------------------
extern "C" void kernel_launch(void* const* d_in, const int* in_sizes, int n_in,
                              void* d_out, int out_size, void* d_ws, size_t ws_size,
                              hipStream_t stream) {
  (void)in_sizes; (void)n_in; (void)out_size;
  const float* dec = (const float*)d_in[0];   // [16,1024,512]
  const float* enc = (const float*)d_in[1];   // [16,4096,512]
  const float* Wa  = (const float*)d_in[2];   // [512,512]
  // b_a constant along softmax axis -> cancels exactly; unused.

  float* ctx   = (float*)d_out;                                   // [16,1024,512]
  float* align = ctx + (long long)B_ * TQ_ * D_;                  // [16,1024,4096]

  char* ws = (char*)d_ws;
  const size_t SZ_ENCT = (size_t)B_ * D_ * TK_ * 2;   // 67,108,864
  const size_t SZ_DEC2 = (size_t)B_ * TQ_ * D_ * 2;   // 16,777,216
  const size_t SZ_ENCF = (size_t)B_ * TK_ * D_ * 2;   // 67,108,864
  const size_t SZ_P16  = (size_t)B_ * TQ_ * TK_ * 2;  // 134,217,728
  const size_t SZ_WB   = (size_t)D_ * D_ * 2;         // 524,288

  _Float16* encT  = (_Float16*)(ws);
  _Float16* dec2h = (_Float16*)(ws + SZ_ENCT);
  _Float16* dec2l = (_Float16*)(ws + SZ_ENCT + SZ_DEC2);
  _Float16* encF  = (_Float16*)(ws + SZ_ENCT + 2 * SZ_DEC2);
  // P16 overlays dec2h/dec2l/encF -- all dead once score finishes (stream order)
  _Float16* p16   = (_Float16*)(ws + SZ_ENCT);
  // presplit planes live past the p16 region (never overlapped)
  u16* dech = (u16*)(ws + SZ_ENCT + SZ_P16);
  u16* decl = dech + (size_t)B_ * TQ_ * D_;
  u16* Wh   = decl + (size_t)B_ * TQ_ * D_;
  u16* Wl   = Wh + (size_t)D_ * D_;

  const bool mid  = ws_size >= SZ_ENCT + 2 * SZ_DEC2 + SZ_ENCF;        // 167.8 MB
  const bool full = ws_size >= SZ_ENCT + SZ_P16;                        // 201.3 MB
  const bool pre  = ws_size >= SZ_ENCT + SZ_P16 + 2 * SZ_DEC2 + 2 * SZ_WB;  // 236 MB

  // 1) encT[b][d][k] = f16(enc[b][k][d]); also encF16[b][k][d] if room
  transpose_conv_kernel<<<dim3(TK_ / 64, D_ / 64, B_), 256, 0, stream>>>(
      enc, encT, mid ? encF : nullptr);

  // 2) dec2 = dec @ W^T (split-bf16 triple) -> f16 hi/lo planes
  if (pre) {
    split_planes_kernel<<<dim3((B_ * TQ_ * D_ / 8) / 256), 256, 0, stream>>>(
        dec, dech, decl, B_ * TQ_ * D_ / 8);
    split_planes_kernel<<<dim3((D_ * D_ / 8) / 256), 256, 0, stream>>>(
        Wa, Wh, Wl, D_ * D_ / 8);
    gemm_dec2p_kernel<<<dim3(D_ / D2BN, (B_ * TQ_) / D2BM), 256, 0, stream>>>(
        dech, decl, Wh, Wl, dec2h, dec2l);
  } else {
    gemm_dec2_kernel<<<dim3(D_ / DBN, (B_ * TQ_) / DBM), 256, 0, stream>>>(
        dec, Wa, dec2h, dec2l);
  }

  // 3) score = dec2 @ enc^T (f16: Ah*B + Al*B)
  if (mid)
    gemm_score_kernel<true><<<dim3(TK_ / SBN, TQ_ / SBM, B_), 256, 0, stream>>>(
        dec2h, dec2l, enc, encF, align);
  else
    gemm_score_kernel<false><<<dim3(TK_ / SBN, TQ_ / SBM, B_), 256, 0, stream>>>(
        dec2h, dec2l, enc, nullptr, align);

  // 4) softmax rows in place (+ f16 copy if room)
  if (full)
    softmax_kernel<true><<<B_ * TQ_, 256, 0, stream>>>(align, p16);
  else
    softmax_kernel<false><<<B_ * TQ_, 256, 0, stream>>>(align, nullptr);

  // 5) ctx = P @ encT^T (f16), 1-D grid with XCD chunk swizzle
  if (full)
    gemm_ctx_kernel<true><<<dim3((TQ_ / CBM) * (D_ / CBN) * B_), 256, 0, stream>>>(
        align, p16, encT, ctx);
  else
    gemm_ctx_kernel<false><<<dim3((TQ_ / CBM) * (D_ / CBN) * B_), 256, 0, stream>>>(
        align, nullptr, encT, ctx);
}

// Round 6
// 850.811 us; speedup vs baseline: 1.0954x; 1.0025x over previous
//
#include <hip/hip_runtime.h>
#include <hip/hip_bf16.h>

#define B_  16
#define TQ_ 1024
#define TK_ 4096
#define D_  512

typedef unsigned short u16;
typedef __attribute__((ext_vector_type(8))) short short8;      // 8 bf16
typedef __attribute__((ext_vector_type(8))) _Float16 f16x8;    // 8 f16 (4 VGPRs)
typedef __attribute__((ext_vector_type(4))) float f32x4;

__device__ __forceinline__ u16 bf16_rne(float x) {
  unsigned u = __float_as_uint(x);
  u += 0x7FFFu + ((u >> 16) & 1u);
  return (u16)(u >> 16);
}
__device__ __forceinline__ float bf16_as_f32(u16 h) {
  return __uint_as_float(((unsigned)h) << 16);
}
__device__ __forceinline__ void split_bf16(float x, u16& h, u16& l) {
  u16 hh = bf16_rne(x);
  h = hh;
  l = bf16_rne(x - bf16_as_f32(hh));
}

// async global->LDS, 16B per lane; LDS dest must be wave-contiguous (base + lane*16)
__device__ __forceinline__ void glld16(const void* g, void* lds) {
  __builtin_amdgcn_global_load_lds(
      (const __attribute__((address_space(1))) unsigned int*)g,
      (__attribute__((address_space(3))) unsigned int*)lds, 16, 0, 0);
}

// 4-slot swizzle (64B rows, BK=32): LDS slot (row,s) holds global segment
// s ^ (row&3) ^ ((row>>2)&3). Staging lane l fetches segment seg_src4(l);
// reads use slot qd ^ (ln&3) ^ (ln>>2). Max 2-way aliasing (free, m136).
__device__ __forceinline__ int seg_src4(int l) {
  return (l & 3) ^ ((l >> 2) & 3) ^ ((l >> 4) & 3);
}

// ---------------------------------------------------------------------------
// x fp32 -> hi/lo bf16 planes (vectorized, 8 elems/thread)
// ---------------------------------------------------------------------------
__global__ __launch_bounds__(256) void split_planes_kernel(
    const float* __restrict__ X, u16* __restrict__ H, u16* __restrict__ L,
    int n8)
{
  int i = blockIdx.x * 256 + threadIdx.x;
  if (i >= n8) return;
  const float4* src = (const float4*)X + (size_t)i * 2;
  float4 a = src[0], b = src[1];
  __align__(16) u16 h[8], l[8];
  split_bf16(a.x, h[0], l[0]);
  split_bf16(a.y, h[1], l[1]);
  split_bf16(a.z, h[2], l[2]);
  split_bf16(a.w, h[3], l[3]);
  split_bf16(b.x, h[4], l[4]);
  split_bf16(b.y, h[5], l[5]);
  split_bf16(b.z, h[6], l[6]);
  split_bf16(b.w, h[7], l[7]);
  *(uint4*)&H[(size_t)i * 8] = *(const uint4*)h;
  *(uint4*)&L[(size_t)i * 8] = *(const uint4*)l;
}

// ---------------------------------------------------------------------------
// enc [b][k][d] fp32 -> encT [b][d][k] f16  (+ optional encF16 [b][k][d] f16)
// ---------------------------------------------------------------------------
__global__ __launch_bounds__(256) void transpose_conv_kernel(
    const float* __restrict__ E, _Float16* __restrict__ ET,
    _Float16* __restrict__ EF)
{
  __shared__ float tile[64][65];
  const int b  = blockIdx.z;
  const int k0 = blockIdx.x * 64;
  const int d0 = blockIdx.y * 64;
  const float* Eb = E + (long long)b * TK_ * D_;
  _Float16* ETb = ET + (long long)b * D_ * TK_;

  const int t  = threadIdx.x;
  const int r  = t >> 2;          // 0..63
  const int c4 = (t & 3) * 16;    // 0,16,32,48

  __align__(16) _Float16 g[16];
  #pragma unroll
  for (int i = 0; i < 16; i += 4) {
    float4 v = *(const float4*)&Eb[(long long)(k0 + r) * D_ + d0 + c4 + i];
    tile[r][c4 + i + 0] = v.x;
    tile[r][c4 + i + 1] = v.y;
    tile[r][c4 + i + 2] = v.z;
    tile[r][c4 + i + 3] = v.w;
    g[i + 0] = (_Float16)v.x;
    g[i + 1] = (_Float16)v.y;
    g[i + 2] = (_Float16)v.z;
    g[i + 3] = (_Float16)v.w;
  }
  if (EF) {
    _Float16* EFb = EF + (long long)b * TK_ * D_;
    uint4* dstF = (uint4*)&EFb[(long long)(k0 + r) * D_ + d0 + c4];
    dstF[0] = ((const uint4*)g)[0];
    dstF[1] = ((const uint4*)g)[1];
  }
  __syncthreads();

  __align__(16) _Float16 h[16];
  #pragma unroll
  for (int i = 0; i < 16; ++i) h[i] = (_Float16)tile[c4 + i][r];
  uint4* dst = (uint4*)&ETb[(long long)(d0 + r) * TK_ + k0 + c4];
  dst[0] = ((const uint4*)h)[0];
  dst[1] = ((const uint4*)h)[1];
}

// ---------------------------------------------------------------------------
// dec2 = dec @ W^T  -- PRESPLIT path, 2-buffer pipeline (fully unrolled,
// static buffer indices), stage(t+1) at top, one __syncthreads per iter.
// Tile 64x128, BK=32, 256 thr (4 waves 2x2), 48 KB LDS.
// ---------------------------------------------------------------------------
#define D2BM 64
#define D2BN 128
#define D2BK 32
#define D2NT (D_ / D2BK)   // 16

__global__ __launch_bounds__(256) void gemm_dec2p_kernel(
    const u16* __restrict__ Ahp, const u16* __restrict__ Alp,
    const u16* __restrict__ Bhp, const u16* __restrict__ Blp,
    _Float16* __restrict__ Ch, _Float16* __restrict__ Cl)
{
  __shared__ u16 sAh[2][D2BM * D2BK];   // 2 x 4 KB
  __shared__ u16 sAl[2][D2BM * D2BK];   // 2 x 4 KB
  __shared__ u16 sBh[2][D2BN * D2BK];   // 2 x 8 KB
  __shared__ u16 sBl[2][D2BN * D2BK];   // 2 x 8 KB

  const int m0 = blockIdx.y * D2BM;
  const int n0 = blockIdx.x * D2BN;

  const int t    = threadIdx.x;
  const int lane = t & 63;
  const int wave = t >> 6;             // 0..3
  const int wrm  = (wave >> 1) * 32;   // 0,32
  const int wcn  = (wave & 1) * 64;    // 0,64
  const int ln   = lane & 15;
  const int qd   = lane >> 4;
  const int sw   = qd ^ (ln & 3) ^ (ln >> 2);

  f32x4 acc[2][4];
  #pragma unroll
  for (int i = 0; i < 2; ++i)
    #pragma unroll
    for (int j = 0; j < 4; ++j) { f32x4 z = {0.f,0.f,0.f,0.f}; acc[i][j] = z; }

  const int ab = seg_src4(lane) * 16;
  const char* gAh = (const char*)Ahp + (long long)(m0 + wave * 16 + (lane >> 2)) * D_ * 2 + ab;
  const char* gAl = (const char*)Alp + (long long)(m0 + wave * 16 + (lane >> 2)) * D_ * 2 + ab;
  const int adst = wave * 1024 + lane * 16;
  const char* gBh = (const char*)Bhp + (long long)(n0 + wave * 32 + (lane >> 2)) * D_ * 2 + ab;
  const char* gBl = (const char*)Blp + (long long)(n0 + wave * 32 + (lane >> 2)) * D_ * 2 + ab;
  const long long rstep = (long long)16 * D_ * 2;
  const int bdst = wave * 2048 + lane * 16;

  auto stage = [&](int buf, int k0) {
    const long long ko = (long long)k0 * 2;
    glld16(gAh + ko, (char*)sAh[buf] + adst);
    glld16(gAl + ko, (char*)sAl[buf] + adst);
    glld16(gBh + ko, (char*)sBh[buf] + bdst);
    glld16(gBh + ko + rstep, (char*)sBh[buf] + bdst + 1024);
    glld16(gBl + ko, (char*)sBl[buf] + bdst);
    glld16(gBl + ko + rstep, (char*)sBl[buf] + bdst + 1024);
  };

  stage(0, 0);
  __syncthreads();

  #pragma unroll
  for (int tt = 0; tt < D2NT; ++tt) {
    const int cur = tt & 1;                       // compile-time after unroll
    if (tt + 1 < D2NT) stage(cur ^ 1, (tt + 1) * D2BK);
    __builtin_amdgcn_sched_barrier(0);            // pin stage loads early

    short8 fah[2], fal[2], fbh[4], fbl[4];
    #pragma unroll
    for (int i = 0; i < 2; ++i) {
      const int ra = (wrm + i * 16 + ln) * D2BK + sw * 8;
      fah[i] = *(const short8*)&sAh[cur][ra];
      fal[i] = *(const short8*)&sAl[cur][ra];
    }
    #pragma unroll
    for (int j = 0; j < 4; ++j) {
      const int rb = (wcn + j * 16 + ln) * D2BK + sw * 8;
      fbh[j] = *(const short8*)&sBh[cur][rb];
      fbl[j] = *(const short8*)&sBl[cur][rb];
    }
    __builtin_amdgcn_s_setprio(1);
    #pragma unroll
    for (int i = 0; i < 2; ++i)
      #pragma unroll
      for (int j = 0; j < 4; ++j) {
        acc[i][j] = __builtin_amdgcn_mfma_f32_16x16x32_bf16(fah[i], fbh[j], acc[i][j], 0, 0, 0);
        acc[i][j] = __builtin_amdgcn_mfma_f32_16x16x32_bf16(fah[i], fbl[j], acc[i][j], 0, 0, 0);
        acc[i][j] = __builtin_amdgcn_mfma_f32_16x16x32_bf16(fal[i], fbh[j], acc[i][j], 0, 0, 0);
      }
    __builtin_amdgcn_s_setprio(0);
    __syncthreads();   // drains the in-flight stage (flew during compute)
  }

  #pragma unroll
  for (int i = 0; i < 2; ++i)
    #pragma unroll
    for (int j = 0; j < 4; ++j)
      #pragma unroll
      for (int rg = 0; rg < 4; ++rg) {
        int row = m0 + wrm + i * 16 + qd * 4 + rg;
        int col = n0 + wcn + j * 16 + ln;
        float x = acc[i][j][rg];
        _Float16 h = (_Float16)x;
        _Float16 l = (_Float16)(x - (float)h);
        long long idx = (long long)row * D_ + col;
        Ch[idx] = h;
        Cl[idx] = l;
      }
}

// ---------------------------------------------------------------------------
// dec2 fallback (in-kernel split): original split-bf16 triple
// ---------------------------------------------------------------------------
#define DBM 128
#define DBN 128
#define DBK 32
#define DPAD 40

__global__ __launch_bounds__(256) void gemm_dec2_kernel(
    const float* __restrict__ A, const float* __restrict__ Bm,
    _Float16* __restrict__ Ch, _Float16* __restrict__ Cl)
{
  __shared__ u16 Ah[DBM * DPAD];
  __shared__ u16 Al[DBM * DPAD];
  __shared__ u16 Bh[DBN * DPAD];
  __shared__ u16 Bl[DBN * DPAD];

  const float* Ab = A  + (long long)(blockIdx.y * DBM) * D_;
  const float* Bb = Bm + (long long)(blockIdx.x * DBN) * D_;

  const int t    = threadIdx.x;
  const int r    = t >> 1;
  const int hf   = t & 1;
  const int lane = t & 63;
  const int wave = t >> 6;
  const int wr   = (wave >> 1) * 64;
  const int wc   = (wave & 1) * 64;
  const int ln   = lane & 15;
  const int qd   = lane >> 4;

  f32x4 acc[4][4];
  #pragma unroll
  for (int i = 0; i < 4; ++i)
    #pragma unroll
    for (int j = 0; j < 4; ++j) { f32x4 z = {0.f,0.f,0.f,0.f}; acc[i][j] = z; }

  const float* srcA = Ab + (long long)r * D_ + hf * 16;
  const float* srcB = Bb + (long long)r * D_ + hf * 16;
  u16* dAh = &Ah[r * DPAD + hf * 16];
  u16* dAl = &Al[r * DPAD + hf * 16];
  u16* dBh = &Bh[r * DPAD + hf * 16];
  u16* dBl = &Bl[r * DPAD + hf * 16];

  for (int k0 = 0; k0 < D_; k0 += DBK) {
    {
      __align__(16) u16 h[16], l[16];
      #pragma unroll
      for (int i = 0; i < 16; i += 4) {
        float4 v = *(const float4*)(srcA + k0 + i);
        split_bf16(v.x, h[i+0], l[i+0]);
        split_bf16(v.y, h[i+1], l[i+1]);
        split_bf16(v.z, h[i+2], l[i+2]);
        split_bf16(v.w, h[i+3], l[i+3]);
      }
      ((uint4*)dAh)[0] = ((const uint4*)h)[0];
      ((uint4*)dAh)[1] = ((const uint4*)h)[1];
      ((uint4*)dAl)[0] = ((const uint4*)l)[0];
      ((uint4*)dAl)[1] = ((const uint4*)l)[1];
      #pragma unroll
      for (int i = 0; i < 16; i += 4) {
        float4 v = *(const float4*)(srcB + k0 + i);
        split_bf16(v.x, h[i+0], l[i+0]);
        split_bf16(v.y, h[i+1], l[i+1]);
        split_bf16(v.z, h[i+2], l[i+2]);
        split_bf16(v.w, h[i+3], l[i+3]);
      }
      ((uint4*)dBh)[0] = ((const uint4*)h)[0];
      ((uint4*)dBh)[1] = ((const uint4*)h)[1];
      ((uint4*)dBl)[0] = ((const uint4*)l)[0];
      ((uint4*)dBl)[1] = ((const uint4*)l)[1];
    }
    __syncthreads();

    short8 fah[4], fal[4], fbh[4], fbl[4];
    #pragma unroll
    for (int i = 0; i < 4; ++i) {
      int ra = (wr + i * 16 + ln) * DPAD + qd * 8;
      int rb = (wc + i * 16 + ln) * DPAD + qd * 8;
      fah[i] = *(const short8*)&Ah[ra];
      fal[i] = *(const short8*)&Al[ra];
      fbh[i] = *(const short8*)&Bh[rb];
      fbl[i] = *(const short8*)&Bl[rb];
    }
    #pragma unroll
    for (int i = 0; i < 4; ++i)
      #pragma unroll
      for (int j = 0; j < 4; ++j) {
        acc[i][j] = __builtin_amdgcn_mfma_f32_16x16x32_bf16(fah[i], fbh[j], acc[i][j], 0, 0, 0);
        acc[i][j] = __builtin_amdgcn_mfma_f32_16x16x32_bf16(fah[i], fbl[j], acc[i][j], 0, 0, 0);
        acc[i][j] = __builtin_amdgcn_mfma_f32_16x16x32_bf16(fal[i], fbh[j], acc[i][j], 0, 0, 0);
      }
    __syncthreads();
  }

  const int m0 = blockIdx.y * DBM;
  const int n0 = blockIdx.x * DBN;
  #pragma unroll
  for (int i = 0; i < 4; ++i)
    #pragma unroll
    for (int j = 0; j < 4; ++j)
      #pragma unroll
      for (int rg = 0; rg < 4; ++rg) {
        int row = m0 + wr + i * 16 + qd * 4 + rg;
        int col = n0 + wc + j * 16 + ln;
        float x = acc[i][j][rg];
        _Float16 h = (_Float16)x;
        _Float16 l = (_Float16)(x - (float)h);
        long long idx = (long long)row * D_ + col;
        Ch[idx] = h;
        Cl[idx] = l;
      }
}

// ---------------------------------------------------------------------------
// Score GEMM: C[b][q][k] = sum_d dec2[b,q,d] * enc[b,k,d]
// 2-buffer pipeline, FULLY UNROLLED (static buffer indices + immediate
// k-offsets -> no per-iter VALU, unlike R2). stage(t+1) at top (pinned by
// sched_barrier), compute t, one __syncthreads at end (drain flies under
// compute). 48 KB LDS; occupancy is VGPR-limited (~3 blk/CU) so no loss.
// ---------------------------------------------------------------------------
#define SBM 128
#define SBN 128
#define SBK 32
#define S_NT (D_ / SBK)   // 16

template<bool F16B>
__global__ __launch_bounds__(256) void gemm_score_kernel(
    const _Float16* __restrict__ A_h, const _Float16* __restrict__ A_l,
    const float* __restrict__ Bf, const _Float16* __restrict__ B16,
    float* __restrict__ C)
{
  __shared__ _Float16 sAh[2][SBM * SBK];   // 2 x 8 KB
  __shared__ _Float16 sAl[2][SBM * SBK];   // 2 x 8 KB
  __shared__ _Float16 sB [2][SBN * SBK];   // 2 x 8 KB

  const int bz = blockIdx.z;
  const int m0 = blockIdx.y * SBM;
  const int n0 = blockIdx.x * SBN;
  const _Float16* Ahb = A_h + (long long)bz * TQ_ * D_ + (long long)m0 * D_;
  const _Float16* Alb = A_l + (long long)bz * TQ_ * D_ + (long long)m0 * D_;

  const int t    = threadIdx.x;
  const int lane = t & 63;
  const int wave = t >> 6;
  const int wr   = (wave >> 1) * 64;
  const int wc   = (wave & 1) * 64;
  const int ln   = lane & 15;
  const int qd   = lane >> 4;
  const int sw   = qd ^ (ln & 3) ^ (ln >> 2);   // swizzled k-slot for reads

  f32x4 acc[4][4];
  #pragma unroll
  for (int i = 0; i < 4; ++i)
    #pragma unroll
    for (int j = 0; j < 4; ++j) { f32x4 z = {0.f,0.f,0.f,0.f}; acc[i][j] = z; }

  // glld mapping: wave handles chunks {2w,2w+1}; lane l -> row 16c+(l>>2),
  // global segment seg_src4(l), LDS linear dest = base + l*16.
  const int c0   = wave * 2;
  const int arow = c0 * 16 + (lane >> 2);
  const int ab   = seg_src4(lane) * 16;
  const char* gAh = (const char*)Ahb + (long long)arow * D_ * 2 + ab;
  const char* gAl = (const char*)Alb + (long long)arow * D_ * 2 + ab;
  const long long rstep = (long long)16 * D_ * 2;   // +16 rows
  const int dstoff = c0 * 1024 + lane * 16;

  const char* gB16 = nullptr;
  if constexpr (F16B) {
    const _Float16* Bb16 = B16 + (long long)bz * TK_ * D_ + (long long)n0 * D_;
    gB16 = (const char*)Bb16 + (long long)arow * D_ * 2 + ab;
  }

  // fallback B staging: thread t -> row t>>1, half t&1; swizzled store slots
  const float* Bb = Bf + (long long)bz * TK_ * D_ + (long long)n0 * D_;
  const int brow = t >> 1;
  const int bhf  = t & 1;
  const float* srcB = Bb + (long long)brow * D_ + bhf * 16;
  const int bh2 = (brow & 3) ^ ((brow >> 2) & 3);
  const int db0 = brow * SBK + ((2 * bhf    ) ^ bh2) * 8;
  const int db1 = brow * SBK + ((2 * bhf + 1) ^ bh2) * 8;

  auto stage = [&](int buf, int k0) {
    const long long ko = (long long)k0 * 2;
    char* dAh = (char*)sAh[buf] + dstoff;
    char* dAl = (char*)sAl[buf] + dstoff;
    glld16(gAh + ko, dAh);
    glld16(gAh + ko + rstep, dAh + 1024);
    glld16(gAl + ko, dAl);
    glld16(gAl + ko + rstep, dAl + 1024);
    if constexpr (F16B) {
      char* dBv = (char*)sB[buf] + dstoff;
      glld16(gB16 + ko, dBv);
      glld16(gB16 + ko + rstep, dBv + 1024);
    } else {
      __align__(16) _Float16 hb[16];
      #pragma unroll
      for (int i = 0; i < 16; i += 4) {
        float4 v = *(const float4*)(srcB + k0 + i);
        hb[i+0] = (_Float16)v.x;
        hb[i+1] = (_Float16)v.y;
        hb[i+2] = (_Float16)v.z;
        hb[i+3] = (_Float16)v.w;
      }
      *(uint4*)&sB[buf][db0] = ((const uint4*)hb)[0];
      *(uint4*)&sB[buf][db1] = ((const uint4*)hb)[1];
    }
  };

  stage(0, 0);
  __syncthreads();

  #pragma unroll
  for (int tt = 0; tt < S_NT; ++tt) {
    const int cur = tt & 1;                       // compile-time after unroll
    if (tt + 1 < S_NT) stage(cur ^ 1, (tt + 1) * SBK);
    __builtin_amdgcn_sched_barrier(0);            // pin stage loads early

    f16x8 fah[4], fal[4], fb[4];
    #pragma unroll
    for (int i = 0; i < 4; ++i) {
      const int ra = (wr + i * 16 + ln) * SBK + sw * 8;
      const int rb = (wc + i * 16 + ln) * SBK + sw * 8;
      fah[i] = *(const f16x8*)&sAh[cur][ra];
      fal[i] = *(const f16x8*)&sAl[cur][ra];
      fb[i]  = *(const f16x8*)&sB[cur][rb];
    }
    __builtin_amdgcn_s_setprio(1);
    #pragma unroll
    for (int i = 0; i < 4; ++i)
      #pragma unroll
      for (int j = 0; j < 4; ++j) {
        acc[i][j] = __builtin_amdgcn_mfma_f32_16x16x32_f16(fah[i], fb[j], acc[i][j], 0, 0, 0);
        acc[i][j] = __builtin_amdgcn_mfma_f32_16x16x32_f16(fal[i], fb[j], acc[i][j], 0, 0, 0);
      }
    __builtin_amdgcn_s_setprio(0);
    __syncthreads();   // drains the in-flight stage (flew during compute)
  }

  float* Cb = C + (long long)bz * TQ_ * TK_;
  #pragma unroll
  for (int i = 0; i < 4; ++i)
    #pragma unroll
    for (int j = 0; j < 4; ++j)
      #pragma unroll
      for (int rg = 0; rg < 4; ++rg) {
        int row = m0 + wr + i * 16 + qd * 4 + rg;
        int col = n0 + wc + j * 16 + ln;
        Cb[(long long)row * TK_ + col] = acc[i][j][rg];
      }
}

// ---------------------------------------------------------------------------
// Row softmax in place (+ optional f16 copy for ctx GEMM)
// ---------------------------------------------------------------------------
template<bool WP16>
__global__ __launch_bounds__(256) void softmax_kernel(
    float* __restrict__ P, _Float16* __restrict__ P16)
{
  __shared__ float red[8];
  float* p = P + (long long)blockIdx.x * TK_;
  const int t    = threadIdx.x;
  const int lane = t & 63;
  const int wave = t >> 6;

  float4 v[4];
  float mx = -3.0e38f;
  #pragma unroll
  for (int i = 0; i < 4; ++i) {
    v[i] = *(const float4*)&p[i * 1024 + t * 4];
    mx = fmaxf(mx, fmaxf(fmaxf(v[i].x, v[i].y), fmaxf(v[i].z, v[i].w)));
  }
  #pragma unroll
  for (int o = 32; o > 0; o >>= 1) mx = fmaxf(mx, __shfl_xor(mx, o, 64));
  if (lane == 0) red[wave] = mx;
  __syncthreads();
  mx = fmaxf(fmaxf(red[0], red[1]), fmaxf(red[2], red[3]));

  float s = 0.f;
  #pragma unroll
  for (int i = 0; i < 4; ++i) {
    v[i].x = __expf(v[i].x - mx);
    v[i].y = __expf(v[i].y - mx);
    v[i].z = __expf(v[i].z - mx);
    v[i].w = __expf(v[i].w - mx);
    s += (v[i].x + v[i].y) + (v[i].z + v[i].w);
  }
  #pragma unroll
  for (int o = 32; o > 0; o >>= 1) s += __shfl_xor(s, o, 64);
  if (lane == 0) red[4 + wave] = s;
  __syncthreads();
  s = (red[4] + red[5]) + (red[6] + red[7]);
  const float inv = 1.0f / s;

  _Float16* p16 = WP16 ? (P16 + (long long)blockIdx.x * TK_) : nullptr;
  #pragma unroll
  for (int i = 0; i < 4; ++i) {
    v[i].x *= inv; v[i].y *= inv; v[i].z *= inv; v[i].w *= inv;
    *(float4*)&p[i * 1024 + t * 4] = v[i];
    if constexpr (WP16) {
      union { _Float16 h[4]; uint2 u; } pk;
      pk.h[0] = (_Float16)v[i].x;
      pk.h[1] = (_Float16)v[i].y;
      pk.h[2] = (_Float16)v[i].z;
      pk.h[3] = (_Float16)v[i].w;
      *(uint2*)&p16[i * 1024 + t * 4] = pk.u;
    }
  }
}

// ---------------------------------------------------------------------------
// Context GEMM: C[b][q][d] = sum_k P[b,q,k] * encT[b,d,k]
// Tile 64x128, CBK=32, 256 thr (4 waves 2x2). 3-buffer counted-vmcnt
// pipeline, 36 KB LDS -> 4 blocks/CU. 3 glld/wave/stage, vmcnt(3).
// Grid 1024, XCD-chunked, m-fastest decode. (R4-proven, unchanged.)
// ---------------------------------------------------------------------------
#define CBM 64
#define CBN 128
#define CBK 32
#define C_NT (TK_ / CBK)   // 128

template<bool F16A>
__global__ __launch_bounds__(256) void gemm_ctx_kernel(
    const float* __restrict__ P, const _Float16* __restrict__ P16,
    const _Float16* __restrict__ ET, float* __restrict__ C)
{
  __shared__ _Float16 sA[3][CBM * CBK];   // 3 x 4 KB
  __shared__ _Float16 sB[3][CBN * CBK];   // 3 x 8 KB

  const int bid = blockIdx.x;
  const int s   = (bid & 7) * 128 + (bid >> 3);
  const int m0  = (s & 15) * CBM;
  const int n0  = ((s >> 4) & 3) * CBN;
  const int bz  = s >> 6;

  const float*    Pb = P  + (long long)bz * TQ_ * TK_ + (long long)m0 * TK_;
  const _Float16* Eb = ET + (long long)bz * D_ * TK_  + (long long)n0 * TK_;

  const int t    = threadIdx.x;
  const int lane = t & 63;
  const int wave = t >> 6;        // 0..3
  const int wr   = (wave >> 1) * 32;   // 0,32
  const int wc   = (wave & 1) * 64;    // 0,64
  const int ln   = lane & 15;
  const int qd   = lane >> 4;
  const int sw   = qd ^ (ln & 3) ^ (ln >> 2);   // 4-slot swizzled k-slot

  f32x4 acc[2][4];
  #pragma unroll
  for (int i = 0; i < 2; ++i)
    #pragma unroll
    for (int j = 0; j < 4; ++j) { f32x4 z = {0.f,0.f,0.f,0.f}; acc[i][j] = z; }

  const int ab = seg_src4(lane) * 16;
  const char* gB = (const char*)Eb + ((long long)(wave * 32 + (lane >> 2)) * TK_) * 2 + ab;
  const long long rstepB = (long long)16 * TK_ * 2;
  const int bdst = wave * 2048 + lane * 16;
  const char* gA16 = nullptr;
  if constexpr (F16A) {
    const _Float16* Pb16 = P16 + (long long)bz * TQ_ * TK_ + (long long)m0 * TK_;
    gA16 = (const char*)Pb16 + ((long long)(wave * 16 + (lane >> 2)) * TK_) * 2 + ab;
  }
  const int adst = wave * 1024 + lane * 16;

  const int arowf = t >> 2;
  const int asegf = t & 3;
  const float* gAf = Pb + (long long)arowf * TK_ + asegf * 8;
  const int afoff = arowf * CBK + ((asegf ^ (arowf & 3) ^ ((arowf >> 2) & 3)) * 8);

  auto stage = [&](int buf, int k0) {
    const long long ko = (long long)k0 * 2;
    char* dB = (char*)sB[buf] + bdst;
    glld16(gB + ko, dB);
    glld16(gB + ko + rstepB, dB + 1024);
    if constexpr (F16A) {
      glld16(gA16 + ko, (char*)sA[buf] + adst);
    } else {
      float4 v0 = *(const float4*)(gAf + k0);
      float4 v1 = *(const float4*)(gAf + k0 + 4);
      __align__(16) _Float16 hb[8];
      hb[0] = (_Float16)v0.x; hb[1] = (_Float16)v0.y;
      hb[2] = (_Float16)v0.z; hb[3] = (_Float16)v0.w;
      hb[4] = (_Float16)v1.x; hb[5] = (_Float16)v1.y;
      hb[6] = (_Float16)v1.z; hb[7] = (_Float16)v1.w;
      *(uint4*)&sA[buf][afoff] = *(const uint4*)hb;
    }
  };

  stage(0, 0);
  stage(1, CBK);
  if constexpr (F16A) {
    asm volatile("s_waitcnt vmcnt(3)" ::: "memory");     // tile0's 3 done
  } else {
    asm volatile("s_waitcnt vmcnt(0) lgkmcnt(0)" ::: "memory");
  }
  __builtin_amdgcn_s_barrier();
  __builtin_amdgcn_sched_barrier(0);

  int cur = 0, nxt = 2;
  #pragma unroll 1
  for (int tt = 0; tt < C_NT; ++tt) {
    if (tt + 2 < C_NT) stage(nxt, (tt + 2) * CBK);

    const _Float16* bA  = sA[cur];
    const _Float16* bBv = sB[cur];
    f16x8 fa[2], fb[4];
    #pragma unroll
    for (int i = 0; i < 2; ++i)
      fa[i] = *(const f16x8*)&bA[(wr + i * 16 + ln) * CBK + sw * 8];
    #pragma unroll
    for (int j = 0; j < 4; ++j)
      fb[j] = *(const f16x8*)&bBv[(wc + j * 16 + ln) * CBK + sw * 8];
    __builtin_amdgcn_s_setprio(1);
    #pragma unroll
    for (int i = 0; i < 2; ++i)
      #pragma unroll
      for (int j = 0; j < 4; ++j)
        acc[i][j] = __builtin_amdgcn_mfma_f32_16x16x32_f16(fa[i], fb[j], acc[i][j], 0, 0, 0);
    __builtin_amdgcn_s_setprio(0);
    if (tt + 1 < C_NT) {
      if constexpr (F16A) {
        if (tt + 2 < C_NT) {
          asm volatile("s_waitcnt vmcnt(3)" ::: "memory");  // tile tt+1 landed
        } else {
          asm volatile("s_waitcnt vmcnt(0)" ::: "memory");
        }
      } else {
        asm volatile("s_waitcnt vmcnt(0) lgkmcnt(0)" ::: "memory");
      }
      __builtin_amdgcn_s_barrier();
      __builtin_amdgcn_sched_barrier(0);
    }
    cur = (cur == 2) ? 0 : cur + 1;
    nxt = (nxt == 2) ? 0 : nxt + 1;
  }

  float* Cb = C + (long long)bz * TQ_ * D_;
  #pragma unroll
  for (int i = 0; i < 2; ++i)
    #pragma unroll
    for (int j = 0; j < 4; ++j)
      #pragma unroll
      for (int rg = 0; rg < 4; ++rg) {
        int row = m0 + wr + i * 16 + qd * 4 + rg;
        int col = n0 + wc + j * 16 + ln;
        Cb[(long long)row * D_ + col] = acc[i][j][rg];
      }
}

// ---------------------------------------------------------------------------
extern "C" void kernel_launch(void* const* d_in, const int* in_sizes, int n_in,
                              void* d_out, int out_size, void* d_ws, size_t ws_size,
                              hipStream_t stream) {
  (void)in_sizes; (void)n_in; (void)out_size;
  const float* dec = (const float*)d_in[0];   // [16,1024,512]
  const float* enc = (const float*)d_in[1];   // [16,4096,512]
  const float* Wa  = (const float*)d_in[2];   // [512,512]
  // b_a constant along softmax axis -> cancels exactly; unused.

  float* ctx   = (float*)d_out;                                   // [16,1024,512]
  float* align = ctx + (long long)B_ * TQ_ * D_;                  // [16,1024,4096]

  char* ws = (char*)d_ws;
  const size_t SZ_ENCT = (size_t)B_ * D_ * TK_ * 2;   // 67,108,864
  const size_t SZ_DEC2 = (size_t)B_ * TQ_ * D_ * 2;   // 16,777,216
  const size_t SZ_ENCF = (size_t)B_ * TK_ * D_ * 2;   // 67,108,864
  const size_t SZ_P16  = (size_t)B_ * TQ_ * TK_ * 2;  // 134,217,728
  const size_t SZ_WB   = (size_t)D_ * D_ * 2;         // 524,288

  _Float16* encT  = (_Float16*)(ws);
  _Float16* dec2h = (_Float16*)(ws + SZ_ENCT);
  _Float16* dec2l = (_Float16*)(ws + SZ_ENCT + SZ_DEC2);
  _Float16* encF  = (_Float16*)(ws + SZ_ENCT + 2 * SZ_DEC2);
  // P16 overlays dec2h/dec2l/encF -- all dead once score finishes (stream order)
  _Float16* p16   = (_Float16*)(ws + SZ_ENCT);
  // presplit planes live past the p16 region (never overlapped)
  u16* dech = (u16*)(ws + SZ_ENCT + SZ_P16);
  u16* decl = dech + (size_t)B_ * TQ_ * D_;
  u16* Wh   = decl + (size_t)B_ * TQ_ * D_;
  u16* Wl   = Wh + (size_t)D_ * D_;

  const bool mid  = ws_size >= SZ_ENCT + 2 * SZ_DEC2 + SZ_ENCF;        // 167.8 MB
  const bool full = ws_size >= SZ_ENCT + SZ_P16;                        // 201.3 MB
  const bool pre  = ws_size >= SZ_ENCT + SZ_P16 + 2 * SZ_DEC2 + 2 * SZ_WB;  // 236 MB

  // 1) encT[b][d][k] = f16(enc[b][k][d]); also encF16[b][k][d] if room
  transpose_conv_kernel<<<dim3(TK_ / 64, D_ / 64, B_), 256, 0, stream>>>(
      enc, encT, mid ? encF : nullptr);

  // 2) dec2 = dec @ W^T (split-bf16 triple) -> f16 hi/lo planes
  if (pre) {
    split_planes_kernel<<<dim3((B_ * TQ_ * D_ / 8) / 256), 256, 0, stream>>>(
        dec, dech, decl, B_ * TQ_ * D_ / 8);
    split_planes_kernel<<<dim3((D_ * D_ / 8) / 256), 256, 0, stream>>>(
        Wa, Wh, Wl, D_ * D_ / 8);
    gemm_dec2p_kernel<<<dim3(D_ / D2BN, (B_ * TQ_) / D2BM), 256, 0, stream>>>(
        dech, decl, Wh, Wl, dec2h, dec2l);
  } else {
    gemm_dec2_kernel<<<dim3(D_ / DBN, (B_ * TQ_) / DBM), 256, 0, stream>>>(
        dec, Wa, dec2h, dec2l);
  }

  // 3) score = dec2 @ enc^T (f16: Ah*B + Al*B)
  if (mid)
    gemm_score_kernel<true><<<dim3(TK_ / SBN, TQ_ / SBM, B_), 256, 0, stream>>>(
        dec2h, dec2l, enc, encF, align);
  else
    gemm_score_kernel<false><<<dim3(TK_ / SBN, TQ_ / SBM, B_), 256, 0, stream>>>(
        dec2h, dec2l, enc, nullptr, align);

  // 4) softmax rows in place (+ f16 copy if room)
  if (full)
    softmax_kernel<true><<<B_ * TQ_, 256, 0, stream>>>(align, p16);
  else
    softmax_kernel<false><<<B_ * TQ_, 256, 0, stream>>>(align, nullptr);

  // 5) ctx = P @ encT^T (f16), 1-D grid with XCD chunk swizzle
  if (full)
    gemm_ctx_kernel<true><<<dim3((TQ_ / CBM) * (D_ / CBN) * B_), 256, 0, stream>>>(
        align, p16, encT, ctx);
  else
    gemm_ctx_kernel<false><<<dim3((TQ_ / CBM) * (D_ / CBN) * B_), 256, 0, stream>>>(
        align, nullptr, encT, ctx);
}